// Round 9
// baseline (279.930 us; speedup 1.0000x reference)
//
#include <hip/hip_runtime.h>

// ---------------------------------------------------------------------------
// 3-layer GCN, 5 dispatches:
//  K1: [phase1 bucket-sort (blocks < nchunks)] ∥ [raw gemm1 h1=x0@W1 (rest)]
//  K2: phase2 per-bucket node sort -> row_ptr/cnt/dinv (all 3 layers), eidx
//  K3: gather1 (per-edge FMA with dinv1[s]) + fused gemm2 -> h2 = x1@W2
//  K4: gather2 + fused gemm3 -> h3 = x2@W3
//  K5: gather3 -> out
// x1/x2 live only in LDS (never written to global). dinv applied per-edge so
// gemm1 is CSR-independent and overlaps phase1.
// NOTE (R6): f32 LDS atomicAdd is a serializing slow path on gfx950 — int
// LDS atomics are fast. Never aggregate floats through LDS atomics.
// NOTE (R7): gather is LLC-bandwidth-bound (8xXCD * |h| L2-miss floor);
// deeper unroll than 8 is neutral.
// ---------------------------------------------------------------------------

#define NB   256            // buckets per layer (W = ceil(n/NB) = 196 < 512)
#define NL   3
#define TB   (NB * NL)      // 768 buckets
#define CAPE 6400           // arena capacity per bucket (mean fill ~3125)
#define CH   8192           // edges per phase-1 chunk
#define P1T  512
#define EPT  (CH / P1T)     // 16 edges per thread, in registers
#define P2T  512
#define CAP2 CAPE

__device__ __forceinline__ void decode_chunk(int g, int nc1, int nc2,
                                             const int* s1, const int* d1, int E1,
                                             const int* s2, const int* d2, int E2,
                                             const int* s3, const int* d3, int E3,
                                             const int** src, const int** dst, int* E, int* l,
                                             int* gout) {
    if (g < nc1)            { *src = s1; *dst = d1; *E = E1; *l = 0; }
    else if (g < nc1 + nc2) { *src = s2; *dst = d2; *E = E2; *l = 1; g -= nc1; }
    else                    { *src = s3; *dst = d3; *E = E3; *l = 2; g -= nc1 + nc2; }
    *gout = g;
}

__device__ __forceinline__ void fma4(float4& a, float s, const float4& w) {
    a.x += s * w.x; a.y += s * w.y; a.z += s * w.z; a.w += s * w.w;
}
__device__ __forceinline__ void add4(float4& a, const float4& v) {
    a.x += v.x; a.y += v.y; a.z += v.z; a.w += v.w;
}

// K1: blocks [0, nchunks) run phase1; blocks [nchunks, nchunks+gemmBlks) run
// raw gemm1 (h1 = x0 @ W1, no dinv scale). 16 KB LDS union.
__global__ void __launch_bounds__(P1T) k1_sort_gemm(
        const int* __restrict__ s1, const int* __restrict__ d1, int E1,
        const int* __restrict__ s2, const int* __restrict__ d2, int E2,
        const int* __restrict__ s3, const int* __restrict__ d3, int E3,
        int nc1, int nc2, int nchunks, int W,
        int* __restrict__ gcur, unsigned int* __restrict__ pairBuf,
        const float* __restrict__ x0, const float* __restrict__ W1g,
        float* __restrict__ h1, int n) {
    __shared__ float smem[4096];   // 16 KB: phase1 uses 9.2 KB, gemm uses 16 KB
    if (blockIdx.x < (unsigned)nchunks) {
        int* hist = (int*)smem;
        int* bo   = hist + TB;
        int* lcur = bo + TB;
        for (int i = threadIdx.x; i < TB; i += P1T) hist[i] = 0;
        __syncthreads();
        const int* src; const int* dst; int E, l, g;
        decode_chunk(blockIdx.x, nc1, nc2, s1, d1, E1, s2, d2, E2, s3, d3, E3,
                     &src, &dst, &E, &l, &g);
        const int e0 = g * CH;
        const int lbase = l * NB;
        unsigned pv[EPT];
        int bn[EPT];
        if (E - e0 >= CH) {
            const int4* s4 = (const int4*)(src + e0);
            const int4* d4 = (const int4*)(dst + e0);
#pragma unroll
            for (int w = 0; w < EPT / 4; ++w) {
                int4 sv = s4[threadIdx.x + w * P1T];
                int4 dv = d4[threadIdx.x + w * P1T];
                int q, i = w * 4;
                q = dv.x / W; bn[i+0] = lbase + q; pv[i+0] = ((unsigned)sv.x << 9) | (unsigned)(dv.x - q * W);
                q = dv.y / W; bn[i+1] = lbase + q; pv[i+1] = ((unsigned)sv.y << 9) | (unsigned)(dv.y - q * W);
                q = dv.z / W; bn[i+2] = lbase + q; pv[i+2] = ((unsigned)sv.z << 9) | (unsigned)(dv.z - q * W);
                q = dv.w / W; bn[i+3] = lbase + q; pv[i+3] = ((unsigned)sv.w << 9) | (unsigned)(dv.w - q * W);
            }
        } else {
#pragma unroll
            for (int i = 0; i < EPT; ++i) {
                int e = e0 + threadIdx.x + i * P1T;
                if (e < E) {
                    int s = src[e], d = dst[e];
                    int q = d / W;
                    bn[i] = lbase + q;
                    pv[i] = ((unsigned)s << 9) | (unsigned)(d - q * W);
                } else bn[i] = -1;
            }
        }
#pragma unroll
        for (int i = 0; i < EPT; ++i)
            if (bn[i] >= 0) atomicAdd(&hist[bn[i]], 1);
        __syncthreads();
        for (int i = threadIdx.x; i < TB; i += P1T) {
            int c = hist[i];
            bo[i] = i * CAPE + (c ? atomicAdd(&gcur[i], c) : 0);
            lcur[i] = 0;
        }
        __syncthreads();
#pragma unroll
        for (int i = 0; i < EPT; ++i) {
            if (bn[i] >= 0) {
                int r = atomicAdd(&lcur[bn[i]], 1);
                int pos = bo[bn[i]] + r;
                if (pos < (bn[i] + 1) * CAPE) pairBuf[pos] = pv[i];  // overflow guard
            }
        }
    } else {
        // raw gemm1: 512 thr, TC=16, TR=32, BR=64, RPT=2
        float* Ws = smem;
        const int bid = blockIdx.x - nchunks;
        for (int i = threadIdx.x; i < 1024; i += P1T)
            ((float4*)Ws)[i] = ((const float4*)W1g)[i];
        __syncthreads();
        const int tc = threadIdx.x % 16;
        const int tr = threadIdx.x / 16;
        const int row0 = bid * 64 + tr * 2;
        const float4* x4 = (const float4*)x0;
        const float4* Ws4 = (const float4*)Ws;
        float4 acc0 = make_float4(0.f, 0.f, 0.f, 0.f), acc1 = acc0;
        const int r0 = min(row0, n - 1), r1 = min(row0 + 1, n - 1);
        for (int k0 = 0; k0 < 64; k0 += 4) {
            float4 wv0 = Ws4[(k0 + 0) * 16 + tc];
            float4 wv1 = Ws4[(k0 + 1) * 16 + tc];
            float4 wv2 = Ws4[(k0 + 2) * 16 + tc];
            float4 wv3 = Ws4[(k0 + 3) * 16 + tc];
            float4 xa = x4[(size_t)r0 * 16 + (k0 / 4)];
            float4 xb = x4[(size_t)r1 * 16 + (k0 / 4)];
            fma4(acc0, xa.x, wv0); fma4(acc0, xa.y, wv1);
            fma4(acc0, xa.z, wv2); fma4(acc0, xa.w, wv3);
            fma4(acc1, xb.x, wv0); fma4(acc1, xb.y, wv1);
            fma4(acc1, xb.z, wv2); fma4(acc1, xb.w, wv3);
        }
        float4* h4 = (float4*)h1;
        if (row0 < n)     h4[(size_t)row0 * 16 + tc] = acc0;
        if (row0 + 1 < n) h4[(size_t)(row0 + 1) * 16 + tc] = acc1;
    }
}

// K2: one wg per bucket: LDS hist -> x4-padded scan -> row_ptr/cnt/dinv,
// place srcs via LDS staging, coalesced int4 eidx output.
__global__ void __launch_bounds__(P2T) phase2(
        const unsigned int* __restrict__ pairBuf, const int* __restrict__ gcur,
        int n, int W,
        int* __restrict__ row_ptr, int* __restrict__ cnt_g,
        float* __restrict__ dinv, int* __restrict__ eidx) {
    __shared__ int lcnt[P2T];
    __shared__ int lscan[P2T];
    __shared__ int stage[CAP2];
    const int bid = blockIdx.x;
    const int l = bid / NB, k = bid % NB;
    const int lo = k * W;
    const int hi = min(n, lo + W);
    const int Wn = hi - lo;                 // <= 196 < P2T
    const int segE = min(gcur[bid], CAPE);
    const size_t base = (size_t)bid * CAPE;
    const int t = threadIdx.x;
    lcnt[t] = 0;
    __syncthreads();
    for (int i = t; i < segE; i += P2T)
        atomicAdd(&lcnt[pairBuf[base + i] & 511u], 1);
    __syncthreads();
    const int v = lcnt[t];
    const int vp = (v + 3) & ~3;            // pad segments to x4
    lscan[t] = vp;
    __syncthreads();
    for (int off = 1; off < P2T; off <<= 1) {
        int add = (t >= off) ? lscan[t - off] : 0;
        __syncthreads();
        lscan[t] += add;
        __syncthreads();
    }
    const int pexcl = lscan[t] - vp;
    const int segEp = lscan[P2T - 1];
    if (t < Wn) {
        int node = l * n + lo + t;
        row_ptr[node] = (int)base + pexcl;
        cnt_g[node] = v;
        dinv[node] = rsqrtf((float)v + 1.0f);   // +1 self-loop
    }
    __syncthreads();
    lcnt[t] = pexcl;
    __syncthreads();
    const bool lds_ok = (segEp <= CAP2);
    for (int i = t; i < segE; i += P2T) {
        unsigned p = pairBuf[base + i];
        int pos = atomicAdd(&lcnt[p & 511u], 1);
        int s = (int)(p >> 9);
        if (lds_ok) stage[pos] = s;
        else if (pos < CAPE) eidx[base + pos] = s;
    }
    __syncthreads();
    if (lds_ok) {
        const int4* st4 = (const int4*)stage;
        int4* e4 = (int4*)(eidx + base);
        int m4 = segEp >> 2;
        for (int i = t; i < m4; i += P2T) e4[i] = st4[i];
    }
}

// K3: gather1 (dinv-weighted FMA over raw h1 rows) + fused gemm2.
// 256 thr = 16 nodes x 16 lanes; x1 row staged in LDS, never global.
__global__ void __launch_bounds__(256) k3_gather1_gemm2(
        const int* __restrict__ row_ptr, const int* __restrict__ cnt,
        const int* __restrict__ eidx, const float* __restrict__ dinv1,
        const float* __restrict__ h1, const float* __restrict__ b1,
        const float* __restrict__ W2g, float* __restrict__ h2, int n) {
    __shared__ float xs[16 * 68];    // 16 nodes x 64 feats, pad 68 (f4-aligned)
    __shared__ float W2s[64 * 32];   // 8 KB
    for (int i = threadIdx.x; i < 512; i += 256)
        ((float4*)W2s)[i] = ((const float4*)W2g)[i];
    const int ln = threadIdx.x >> 4;
    const int f4 = threadIdx.x & 15;
    const int node = blockIdx.x * 16 + ln;
    if (node < n) {
        const int beg = row_ptr[node];
        const int m = cnt[node];
        const float4* h4 = (const float4*)h1;
        float4 a0 = make_float4(0.f, 0.f, 0.f, 0.f), a1 = a0, a2 = a0, a3 = a0;
        int j = 0;
        for (; j + 8 <= m; j += 8) {
            int4 e0 = *(const int4*)(eidx + beg + j);
            int4 e1 = *(const int4*)(eidx + beg + j + 4);
            float w0 = dinv1[e0.x], w1 = dinv1[e0.y], w2 = dinv1[e0.z], w3 = dinv1[e0.w];
            float w4 = dinv1[e1.x], w5 = dinv1[e1.y], w6 = dinv1[e1.z], w7 = dinv1[e1.w];
            float4 v0 = h4[(size_t)e0.x * 16 + f4];
            float4 v1 = h4[(size_t)e0.y * 16 + f4];
            float4 v2 = h4[(size_t)e0.z * 16 + f4];
            float4 v3 = h4[(size_t)e0.w * 16 + f4];
            float4 v4 = h4[(size_t)e1.x * 16 + f4];
            float4 v5 = h4[(size_t)e1.y * 16 + f4];
            float4 v6 = h4[(size_t)e1.z * 16 + f4];
            float4 v7 = h4[(size_t)e1.w * 16 + f4];
            fma4(a0, w0, v0); fma4(a1, w1, v1); fma4(a2, w2, v2); fma4(a3, w3, v3);
            fma4(a0, w4, v4); fma4(a1, w5, v5); fma4(a2, w6, v6); fma4(a3, w7, v7);
        }
        if (j + 4 <= m) {
            int4 e0 = *(const int4*)(eidx + beg + j);
            float w0 = dinv1[e0.x], w1 = dinv1[e0.y], w2 = dinv1[e0.z], w3 = dinv1[e0.w];
            fma4(a0, w0, h4[(size_t)e0.x * 16 + f4]);
            fma4(a1, w1, h4[(size_t)e0.y * 16 + f4]);
            fma4(a2, w2, h4[(size_t)e0.z * 16 + f4]);
            fma4(a3, w3, h4[(size_t)e0.w * 16 + f4]);
            j += 4;
        }
        for (; j < m; ++j) {
            int s = eidx[beg + j];
            fma4(a0, dinv1[s], h4[(size_t)s * 16 + f4]);
        }
        add4(a0, a1); add4(a2, a3); add4(a0, a2);
        float di = dinv1[node];
        float4 self = h4[(size_t)node * 16 + f4];
        float4 bv = ((const float4*)b1)[f4];
        float4 o;
        o.x = di * (a0.x + di * self.x) + bv.x;
        o.y = di * (a0.y + di * self.y) + bv.y;
        o.z = di * (a0.z + di * self.z) + bv.z;
        o.w = di * (a0.w + di * self.w) + bv.w;
        o.x = o.x > 0.f ? o.x : 0.f;
        o.y = o.y > 0.f ? o.y : 0.f;
        o.z = o.z > 0.f ? o.z : 0.f;
        o.w = o.w > 0.f ? o.w : 0.f;
        *(float4*)&xs[ln * 68 + f4 * 4] = o;   // x1 row, LDS only
    }
    __syncthreads();
    if (node < n) {
        const int c0 = f4 * 2;
        float s0 = 0.f, s1 = 0.f;
#pragma unroll
        for (int k = 0; k < 64; ++k) {
            float xv = xs[ln * 68 + k];
            s0 += xv * W2s[k * 32 + c0];
            s1 += xv * W2s[k * 32 + c0 + 1];
        }
        ((float2*)h2)[(size_t)node * 16 + f4] = make_float2(s0, s1);  // raw h2
    }
}

// K4: gather2 + fused gemm3. 256 thr = 32 nodes x 8 lanes.
__global__ void __launch_bounds__(256) k4_gather2_gemm3(
        const int* __restrict__ row_ptr2, const int* __restrict__ cnt2,
        const int* __restrict__ eidx, const float* __restrict__ dinv2,
        const float* __restrict__ h2, const float* __restrict__ b2,
        const float* __restrict__ W3g, float* __restrict__ h3, int n) {
    __shared__ float xs[32 * 36];    // 32 nodes x 32 feats, pad 36
    __shared__ float W3s[32 * 16];   // 2 KB
    for (int i = threadIdx.x; i < 128; i += 256)
        ((float4*)W3s)[i] = ((const float4*)W3g)[i];
    const int ln = threadIdx.x >> 3;
    const int f4 = threadIdx.x & 7;
    const int node = blockIdx.x * 32 + ln;
    if (node < n) {
        const int beg = row_ptr2[node];
        const int m = cnt2[node];
        const float4* h4 = (const float4*)h2;
        float4 a0 = make_float4(0.f, 0.f, 0.f, 0.f), a1 = a0, a2 = a0, a3 = a0;
        int j = 0;
        for (; j + 8 <= m; j += 8) {
            int4 e0 = *(const int4*)(eidx + beg + j);
            int4 e1 = *(const int4*)(eidx + beg + j + 4);
            float w0 = dinv2[e0.x], w1 = dinv2[e0.y], w2 = dinv2[e0.z], w3 = dinv2[e0.w];
            float w4 = dinv2[e1.x], w5 = dinv2[e1.y], w6 = dinv2[e1.z], w7 = dinv2[e1.w];
            fma4(a0, w0, h4[(size_t)e0.x * 8 + f4]);
            fma4(a1, w1, h4[(size_t)e0.y * 8 + f4]);
            fma4(a2, w2, h4[(size_t)e0.z * 8 + f4]);
            fma4(a3, w3, h4[(size_t)e0.w * 8 + f4]);
            fma4(a0, w4, h4[(size_t)e1.x * 8 + f4]);
            fma4(a1, w5, h4[(size_t)e1.y * 8 + f4]);
            fma4(a2, w6, h4[(size_t)e1.z * 8 + f4]);
            fma4(a3, w7, h4[(size_t)e1.w * 8 + f4]);
        }
        if (j + 4 <= m) {
            int4 e0 = *(const int4*)(eidx + beg + j);
            fma4(a0, dinv2[e0.x], h4[(size_t)e0.x * 8 + f4]);
            fma4(a1, dinv2[e0.y], h4[(size_t)e0.y * 8 + f4]);
            fma4(a2, dinv2[e0.z], h4[(size_t)e0.z * 8 + f4]);
            fma4(a3, dinv2[e0.w], h4[(size_t)e0.w * 8 + f4]);
            j += 4;
        }
        for (; j < m; ++j) {
            int s = eidx[beg + j];
            fma4(a0, dinv2[s], h4[(size_t)s * 8 + f4]);
        }
        add4(a0, a1); add4(a2, a3); add4(a0, a2);
        float di = dinv2[node];
        float4 self = h4[(size_t)node * 8 + f4];
        float4 bv = ((const float4*)b2)[f4];
        float4 o;
        o.x = di * (a0.x + di * self.x) + bv.x;
        o.y = di * (a0.y + di * self.y) + bv.y;
        o.z = di * (a0.z + di * self.z) + bv.z;
        o.w = di * (a0.w + di * self.w) + bv.w;
        o.x = o.x > 0.f ? o.x : 0.f;
        o.y = o.y > 0.f ? o.y : 0.f;
        o.z = o.z > 0.f ? o.z : 0.f;
        o.w = o.w > 0.f ? o.w : 0.f;
        *(float4*)&xs[ln * 36 + f4 * 4] = o;   // x2 row, LDS only
    }
    __syncthreads();
    if (node < n) {
        const int c0 = f4 * 2;
        float s0 = 0.f, s1 = 0.f;
#pragma unroll
        for (int k = 0; k < 32; ++k) {
            float xv = xs[ln * 36 + k];
            s0 += xv * W3s[k * 16 + c0];
            s1 += xv * W3s[k * 16 + c0 + 1];
        }
        ((float2*)h3)[(size_t)node * 8 + f4] = make_float2(s0, s1);   // raw h3
    }
}

// K5: gather3 -> out. 256 thr = 64 nodes x 4 lanes.
__global__ void __launch_bounds__(256) k5_gather3(
        const int* __restrict__ row_ptr3, const int* __restrict__ cnt3,
        const int* __restrict__ eidx, const float* __restrict__ dinv3,
        const float* __restrict__ h3, const float* __restrict__ b3,
        float* __restrict__ out, int n) {
    const int ln = threadIdx.x >> 2;
    const int f4 = threadIdx.x & 3;
    const int node = blockIdx.x * 64 + ln;
    if (node >= n) return;
    const int beg = row_ptr3[node];
    const int m = cnt3[node];
    const float4* h4 = (const float4*)h3;
    float4 a0 = make_float4(0.f, 0.f, 0.f, 0.f), a1 = a0, a2 = a0, a3 = a0;
    int j = 0;
    for (; j + 8 <= m; j += 8) {
        int4 e0 = *(const int4*)(eidx + beg + j);
        int4 e1 = *(const int4*)(eidx + beg + j + 4);
        float w0 = dinv3[e0.x], w1 = dinv3[e0.y], w2 = dinv3[e0.z], w3 = dinv3[e0.w];
        float w4 = dinv3[e1.x], w5 = dinv3[e1.y], w6 = dinv3[e1.z], w7 = dinv3[e1.w];
        fma4(a0, w0, h4[(size_t)e0.x * 4 + f4]);
        fma4(a1, w1, h4[(size_t)e0.y * 4 + f4]);
        fma4(a2, w2, h4[(size_t)e0.z * 4 + f4]);
        fma4(a3, w3, h4[(size_t)e0.w * 4 + f4]);
        fma4(a0, w4, h4[(size_t)e1.x * 4 + f4]);
        fma4(a1, w5, h4[(size_t)e1.y * 4 + f4]);
        fma4(a2, w6, h4[(size_t)e1.z * 4 + f4]);
        fma4(a3, w7, h4[(size_t)e1.w * 4 + f4]);
    }
    if (j + 4 <= m) {
        int4 e0 = *(const int4*)(eidx + beg + j);
        fma4(a0, dinv3[e0.x], h4[(size_t)e0.x * 4 + f4]);
        fma4(a1, dinv3[e0.y], h4[(size_t)e0.y * 4 + f4]);
        fma4(a2, dinv3[e0.z], h4[(size_t)e0.z * 4 + f4]);
        fma4(a3, dinv3[e0.w], h4[(size_t)e0.w * 4 + f4]);
        j += 4;
    }
    for (; j < m; ++j) {
        int s = eidx[beg + j];
        fma4(a0, dinv3[s], h4[(size_t)s * 4 + f4]);
    }
    add4(a0, a1); add4(a2, a3); add4(a0, a2);
    float di = dinv3[node];
    float4 self = h4[(size_t)node * 4 + f4];
    float4 bv = ((const float4*)b3)[f4];
    float4 o;
    o.x = di * (a0.x + di * self.x) + bv.x;
    o.y = di * (a0.y + di * self.y) + bv.y;
    o.z = di * (a0.z + di * self.z) + bv.z;
    o.w = di * (a0.w + di * self.w) + bv.w;
    o.x = o.x > 0.f ? o.x : 0.f;
    o.y = o.y > 0.f ? o.y : 0.f;
    o.z = o.z > 0.f ? o.z : 0.f;
    o.w = o.w > 0.f ? o.w : 0.f;
    ((float4*)out)[(size_t)node * 4 + f4] = o;
}

extern "C" void kernel_launch(void* const* d_in, const int* in_sizes, int n_in,
                              void* d_out, int out_size, void* d_ws, size_t ws_size,
                              hipStream_t stream) {
    const float* x0  = (const float*)d_in[0];
    const int*   ei1 = (const int*)d_in[1];
    const int*   ei3 = (const int*)d_in[2];
    const int*   ei9 = (const int*)d_in[3];
    const float* W1  = (const float*)d_in[4];
    const float* b1  = (const float*)d_in[5];
    const float* W2  = (const float*)d_in[6];
    const float* b2  = (const float*)d_in[7];
    const float* W3  = (const float*)d_in[8];
    const float* b3  = (const float*)d_in[9];

    const int n  = in_sizes[0] / 64;  // 50000
    const int E1 = in_sizes[1] / 2;   // 800000
    const int E3 = in_sizes[2] / 2;
    const int E9 = in_sizes[3] / 2;
    const int n3 = 3 * n;
    const int W  = (n + NB - 1) / NB; // 196 (< 512 -> 9-bit local id)

    const int nc1 = (E1 + CH - 1) / CH;
    const int nc2 = (E3 + CH - 1) / CH;
    const int nc3 = (E9 + CH - 1) / CH;
    const int nchunks = nc1 + nc2 + nc3;
    const int gemmBlks = (n + 63) / 64;

    int* gcur    = (int*)d_ws;                           // TB
    unsigned int* pairBuf = (unsigned int*)(gcur + TB);  // TB*CAPE
    int* eidx    = (int*)(pairBuf + (size_t)TB * CAPE);  // TB*CAPE
    int* row_ptr = eidx + (size_t)TB * CAPE;             // 3n
    int* cnt     = row_ptr + n3;                         // 3n
    float* dinv  = (float*)(cnt + n3);                   // 3n
    float* h1    = dinv + n3;                            // n*64
    float* h2    = h1 + (size_t)n * 64;                  // n*32
    float* h3    = h2 + (size_t)n * 32;                  // n*16

    hipMemsetAsync(gcur, 0, TB * sizeof(int), stream);
    k1_sort_gemm<<<nchunks + gemmBlks, P1T, 0, stream>>>(
        ei1, ei1 + E1, E1, ei3, ei3 + E3, E3, ei9, ei9 + E9, E9,
        nc1, nc2, nchunks, W, gcur, pairBuf, x0, W1, h1, n);
    phase2<<<TB, P2T, 0, stream>>>(pairBuf, gcur, n, W, row_ptr, cnt, dinv, eidx);
    k3_gather1_gemm2<<<(n + 15) / 16, 256, 0, stream>>>(
        row_ptr, cnt, eidx, dinv, h1, b1, W2, h2, n);
    k4_gather2_gemm3<<<(n + 31) / 32, 256, 0, stream>>>(
        row_ptr + n, cnt + n, eidx, dinv + n, h2, b2, W3, h3, n);
    k5_gather3<<<(n + 63) / 64, 256, 0, stream>>>(
        row_ptr + 2 * n, cnt + 2 * n, eidx, dinv + 2 * n, h3, b3, (float*)d_out, n);
}

// Round 10
// 203.469 us; speedup vs baseline: 1.3758x; 1.3758x over previous
//
#include <hip/hip_runtime.h>

// ---------------------------------------------------------------------------
// 3-layer GCN, 6 dispatches:
//  K1: phase1 bucket-sort (counting sort into per-bucket arena, dense writes)
//  K1b: raw gemm1 h1 = x0 @ W1 (dinv applied per-edge later)
//  K2: phase2 per-bucket node sort -> row_ptr/cnt/dinv (all 3 layers), eidx
//  K3: gather1 (per-edge FMA with dinv1[s]) + fused gemm2 -> h2 = x1@W2
//  K4: gather2 + fused gemm3 -> h3 = x2@W3
//  K5: gather3 -> out
// x1/x2 live only in LDS (never written to global).
// NOTE (R6): f32 LDS atomicAdd is a serializing slow path on gfx950 — int
// LDS atomics are fast. Never aggregate floats through LDS atomics.
// NOTE (R7): gather is LLC-bandwidth-bound; unroll deeper than 8 is neutral.
// NOTE (R8): NEVER co-schedule streaming traffic with the L2-resident
// scatter of phase1 — gemm1's 25 MB stream evicted partial dirty pairBuf
// lines -> 167 MB write amplification. Keep phase1 isolated.
// ---------------------------------------------------------------------------

#define NB   256            // buckets per layer (W = ceil(n/NB) = 196 < 512)
#define NL   3
#define TB   (NB * NL)      // 768 buckets
#define CAPE 6400           // arena capacity per bucket (mean fill ~3125)
#define CH   8192           // edges per phase-1 chunk
#define P1T  512
#define EPT  (CH / P1T)     // 16 edges per thread, in registers
#define P2T  512
#define CAP2 CAPE

__device__ __forceinline__ void decode_chunk(int g, int nc1, int nc2,
                                             const int* s1, const int* d1, int E1,
                                             const int* s2, const int* d2, int E2,
                                             const int* s3, const int* d3, int E3,
                                             const int** src, const int** dst, int* E, int* l,
                                             int* gout) {
    if (g < nc1)            { *src = s1; *dst = d1; *E = E1; *l = 0; }
    else if (g < nc1 + nc2) { *src = s2; *dst = d2; *E = E2; *l = 1; g -= nc1; }
    else                    { *src = s3; *dst = d3; *E = E3; *l = 2; g -= nc1 + nc2; }
    *gout = g;
}

__device__ __forceinline__ void fma4(float4& a, float s, const float4& w) {
    a.x += s * w.x; a.y += s * w.y; a.z += s * w.z; a.w += s * w.w;
}
__device__ __forceinline__ void add4(float4& a, const float4& v) {
    a.x += v.x; a.y += v.y; a.z += v.z; a.w += v.w;
}

__global__ void __launch_bounds__(P1T) phase1(
        const int* __restrict__ s1, const int* __restrict__ d1, int E1,
        const int* __restrict__ s2, const int* __restrict__ d2, int E2,
        const int* __restrict__ s3, const int* __restrict__ d3, int E3,
        int nc1, int nc2, int W,
        int* __restrict__ gcur, unsigned int* __restrict__ pairBuf) {
    __shared__ int hist[TB];
    __shared__ int bo[TB];
    __shared__ int lcur[TB];
    for (int i = threadIdx.x; i < TB; i += P1T) hist[i] = 0;
    __syncthreads();
    const int* src; const int* dst; int E, l, g;
    decode_chunk(blockIdx.x, nc1, nc2, s1, d1, E1, s2, d2, E2, s3, d3, E3,
                 &src, &dst, &E, &l, &g);
    const int e0 = g * CH;
    const int lbase = l * NB;
    unsigned pv[EPT];
    int bn[EPT];
    if (E - e0 >= CH) {                       // full chunk: int4 register loads
        const int4* s4 = (const int4*)(src + e0);
        const int4* d4 = (const int4*)(dst + e0);
#pragma unroll
        for (int w = 0; w < EPT / 4; ++w) {
            int4 sv = s4[threadIdx.x + w * P1T];
            int4 dv = d4[threadIdx.x + w * P1T];
            int q, i = w * 4;
            q = dv.x / W; bn[i+0] = lbase + q; pv[i+0] = ((unsigned)sv.x << 9) | (unsigned)(dv.x - q * W);
            q = dv.y / W; bn[i+1] = lbase + q; pv[i+1] = ((unsigned)sv.y << 9) | (unsigned)(dv.y - q * W);
            q = dv.z / W; bn[i+2] = lbase + q; pv[i+2] = ((unsigned)sv.z << 9) | (unsigned)(dv.z - q * W);
            q = dv.w / W; bn[i+3] = lbase + q; pv[i+3] = ((unsigned)sv.w << 9) | (unsigned)(dv.w - q * W);
        }
    } else {                                   // tail chunk: guarded scalar loads
#pragma unroll
        for (int i = 0; i < EPT; ++i) {
            int e = e0 + threadIdx.x + i * P1T;
            if (e < E) {
                int s = src[e], d = dst[e];
                int q = d / W;
                bn[i] = lbase + q;
                pv[i] = ((unsigned)s << 9) | (unsigned)(d - q * W);
            } else bn[i] = -1;
        }
    }
#pragma unroll
    for (int i = 0; i < EPT; ++i)
        if (bn[i] >= 0) atomicAdd(&hist[bn[i]], 1);
    __syncthreads();
    for (int i = threadIdx.x; i < TB; i += P1T) {
        int c = hist[i];
        bo[i] = i * CAPE + (c ? atomicAdd(&gcur[i], c) : 0);
        lcur[i] = 0;
    }
    __syncthreads();
#pragma unroll
    for (int i = 0; i < EPT; ++i) {
        if (bn[i] >= 0) {
            int r = atomicAdd(&lcur[bn[i]], 1);
            int pos = bo[bn[i]] + r;
            if (pos < (bn[i] + 1) * CAPE) pairBuf[pos] = pv[i];  // overflow guard
        }
    }
}

// Raw gemm1: h1 = x0 @ W1 (64x64), no dinv. 256 thr, TC=16, RPT=4.
__global__ void __launch_bounds__(256) gemm1_raw(
        const float* __restrict__ x, const float* __restrict__ Wg,
        float* __restrict__ h, int n) {
    __shared__ float Ws[64 * 64];
    for (int i = threadIdx.x; i < 1024; i += 256)
        ((float4*)Ws)[i] = ((const float4*)Wg)[i];
    __syncthreads();
    const int tc = threadIdx.x % 16;
    const int tr = threadIdx.x / 16;
    const int row0 = blockIdx.x * 64 + tr * 4;
    const float4* x4 = (const float4*)x;
    const float4* Ws4 = (const float4*)Ws;
    float4 acc[4];
#pragma unroll
    for (int r = 0; r < 4; ++r) acc[r] = make_float4(0.f, 0.f, 0.f, 0.f);
    int rowc[4];
#pragma unroll
    for (int r = 0; r < 4; ++r) rowc[r] = min(row0 + r, n - 1);
    for (int k0 = 0; k0 < 64; k0 += 4) {
        float4 wv0 = Ws4[(k0 + 0) * 16 + tc];
        float4 wv1 = Ws4[(k0 + 1) * 16 + tc];
        float4 wv2 = Ws4[(k0 + 2) * 16 + tc];
        float4 wv3 = Ws4[(k0 + 3) * 16 + tc];
#pragma unroll
        for (int r = 0; r < 4; ++r) {
            float4 xv = x4[(size_t)rowc[r] * 16 + (k0 / 4)];
            fma4(acc[r], xv.x, wv0);
            fma4(acc[r], xv.y, wv1);
            fma4(acc[r], xv.z, wv2);
            fma4(acc[r], xv.w, wv3);
        }
    }
    float4* h4 = (float4*)h;
#pragma unroll
    for (int r = 0; r < 4; ++r) {
        int row = row0 + r;
        if (row < n) h4[(size_t)row * 16 + tc] = acc[r];
    }
}

// K2: one wg per bucket: LDS hist -> x4-padded scan -> row_ptr/cnt/dinv,
// place srcs via LDS staging, coalesced int4 eidx output.
__global__ void __launch_bounds__(P2T) phase2(
        const unsigned int* __restrict__ pairBuf, const int* __restrict__ gcur,
        int n, int W,
        int* __restrict__ row_ptr, int* __restrict__ cnt_g,
        float* __restrict__ dinv, int* __restrict__ eidx) {
    __shared__ int lcnt[P2T];
    __shared__ int lscan[P2T];
    __shared__ int stage[CAP2];
    const int bid = blockIdx.x;
    const int l = bid / NB, k = bid % NB;
    const int lo = k * W;
    const int hi = min(n, lo + W);
    const int Wn = hi - lo;                 // <= 196 < P2T
    const int segE = min(gcur[bid], CAPE);
    const size_t base = (size_t)bid * CAPE;
    const int t = threadIdx.x;
    lcnt[t] = 0;
    __syncthreads();
    for (int i = t; i < segE; i += P2T)
        atomicAdd(&lcnt[pairBuf[base + i] & 511u], 1);
    __syncthreads();
    const int v = lcnt[t];
    const int vp = (v + 3) & ~3;            // pad segments to x4
    lscan[t] = vp;
    __syncthreads();
    for (int off = 1; off < P2T; off <<= 1) {
        int add = (t >= off) ? lscan[t - off] : 0;
        __syncthreads();
        lscan[t] += add;
        __syncthreads();
    }
    const int pexcl = lscan[t] - vp;
    const int segEp = lscan[P2T - 1];
    if (t < Wn) {
        int node = l * n + lo + t;
        row_ptr[node] = (int)base + pexcl;
        cnt_g[node] = v;
        dinv[node] = rsqrtf((float)v + 1.0f);   // +1 self-loop
    }
    __syncthreads();
    lcnt[t] = pexcl;
    __syncthreads();
    const bool lds_ok = (segEp <= CAP2);
    for (int i = t; i < segE; i += P2T) {
        unsigned p = pairBuf[base + i];
        int pos = atomicAdd(&lcnt[p & 511u], 1);
        int s = (int)(p >> 9);
        if (lds_ok) stage[pos] = s;
        else if (pos < CAPE) eidx[base + pos] = s;
    }
    __syncthreads();
    if (lds_ok) {
        const int4* st4 = (const int4*)stage;
        int4* e4 = (int4*)(eidx + base);
        int m4 = segEp >> 2;
        for (int i = t; i < m4; i += P2T) e4[i] = st4[i];
    }
}

// K3: gather1 (dinv-weighted FMA over raw h1 rows) + fused gemm2.
// 256 thr = 16 nodes x 16 lanes; x1 row staged in LDS, never global.
__global__ void __launch_bounds__(256) k3_gather1_gemm2(
        const int* __restrict__ row_ptr, const int* __restrict__ cnt,
        const int* __restrict__ eidx, const float* __restrict__ dinv1,
        const float* __restrict__ h1, const float* __restrict__ b1,
        const float* __restrict__ W2g, float* __restrict__ h2, int n) {
    __shared__ float xs[16 * 68];    // 16 nodes x 64 feats, pad 68
    __shared__ float W2s[64 * 32];   // 8 KB
    for (int i = threadIdx.x; i < 512; i += 256)
        ((float4*)W2s)[i] = ((const float4*)W2g)[i];
    const int ln = threadIdx.x >> 4;
    const int f4 = threadIdx.x & 15;
    const int node = blockIdx.x * 16 + ln;
    if (node < n) {
        const int beg = row_ptr[node];
        const int m = cnt[node];
        const float4* h4 = (const float4*)h1;
        float4 a0 = make_float4(0.f, 0.f, 0.f, 0.f), a1 = a0, a2 = a0, a3 = a0;
        int j = 0;
        for (; j + 8 <= m; j += 8) {
            int4 e0 = *(const int4*)(eidx + beg + j);
            int4 e1 = *(const int4*)(eidx + beg + j + 4);
            float w0 = dinv1[e0.x], w1 = dinv1[e0.y], w2 = dinv1[e0.z], w3 = dinv1[e0.w];
            float w4 = dinv1[e1.x], w5 = dinv1[e1.y], w6 = dinv1[e1.z], w7 = dinv1[e1.w];
            float4 v0 = h4[(size_t)e0.x * 16 + f4];
            float4 v1 = h4[(size_t)e0.y * 16 + f4];
            float4 v2 = h4[(size_t)e0.z * 16 + f4];
            float4 v3 = h4[(size_t)e0.w * 16 + f4];
            float4 v4 = h4[(size_t)e1.x * 16 + f4];
            float4 v5 = h4[(size_t)e1.y * 16 + f4];
            float4 v6 = h4[(size_t)e1.z * 16 + f4];
            float4 v7 = h4[(size_t)e1.w * 16 + f4];
            fma4(a0, w0, v0); fma4(a1, w1, v1); fma4(a2, w2, v2); fma4(a3, w3, v3);
            fma4(a0, w4, v4); fma4(a1, w5, v5); fma4(a2, w6, v6); fma4(a3, w7, v7);
        }
        if (j + 4 <= m) {
            int4 e0 = *(const int4*)(eidx + beg + j);
            float w0 = dinv1[e0.x], w1 = dinv1[e0.y], w2 = dinv1[e0.z], w3 = dinv1[e0.w];
            fma4(a0, w0, h4[(size_t)e0.x * 16 + f4]);
            fma4(a1, w1, h4[(size_t)e0.y * 16 + f4]);
            fma4(a2, w2, h4[(size_t)e0.z * 16 + f4]);
            fma4(a3, w3, h4[(size_t)e0.w * 16 + f4]);
            j += 4;
        }
        for (; j < m; ++j) {
            int s = eidx[beg + j];
            fma4(a0, dinv1[s], h4[(size_t)s * 16 + f4]);
        }
        add4(a0, a1); add4(a2, a3); add4(a0, a2);
        float di = dinv1[node];
        float4 self = h4[(size_t)node * 16 + f4];
        float4 bv = ((const float4*)b1)[f4];
        float4 o;
        o.x = di * (a0.x + di * self.x) + bv.x;
        o.y = di * (a0.y + di * self.y) + bv.y;
        o.z = di * (a0.z + di * self.z) + bv.z;
        o.w = di * (a0.w + di * self.w) + bv.w;
        o.x = o.x > 0.f ? o.x : 0.f;
        o.y = o.y > 0.f ? o.y : 0.f;
        o.z = o.z > 0.f ? o.z : 0.f;
        o.w = o.w > 0.f ? o.w : 0.f;
        *(float4*)&xs[ln * 68 + f4 * 4] = o;   // x1 row, LDS only
    }
    __syncthreads();
    if (node < n) {
        const int c0 = f4 * 2;
        float s0 = 0.f, s1 = 0.f;
#pragma unroll
        for (int k = 0; k < 64; ++k) {
            float xv = xs[ln * 68 + k];
            s0 += xv * W2s[k * 32 + c0];
            s1 += xv * W2s[k * 32 + c0 + 1];
        }
        ((float2*)h2)[(size_t)node * 16 + f4] = make_float2(s0, s1);  // raw h2
    }
}

// K4: gather2 + fused gemm3. 256 thr = 32 nodes x 8 lanes.
__global__ void __launch_bounds__(256) k4_gather2_gemm3(
        const int* __restrict__ row_ptr2, const int* __restrict__ cnt2,
        const int* __restrict__ eidx, const float* __restrict__ dinv2,
        const float* __restrict__ h2, const float* __restrict__ b2,
        const float* __restrict__ W3g, float* __restrict__ h3, int n) {
    __shared__ float xs[32 * 36];    // 32 nodes x 32 feats, pad 36
    __shared__ float W3s[32 * 16];   // 2 KB
    for (int i = threadIdx.x; i < 128; i += 256)
        ((float4*)W3s)[i] = ((const float4*)W3g)[i];
    const int ln = threadIdx.x >> 3;
    const int f4 = threadIdx.x & 7;
    const int node = blockIdx.x * 32 + ln;
    if (node < n) {
        const int beg = row_ptr2[node];
        const int m = cnt2[node];
        const float4* h4 = (const float4*)h2;
        float4 a0 = make_float4(0.f, 0.f, 0.f, 0.f), a1 = a0, a2 = a0, a3 = a0;
        int j = 0;
        for (; j + 8 <= m; j += 8) {
            int4 e0 = *(const int4*)(eidx + beg + j);
            int4 e1 = *(const int4*)(eidx + beg + j + 4);
            float w0 = dinv2[e0.x], w1 = dinv2[e0.y], w2 = dinv2[e0.z], w3 = dinv2[e0.w];
            float w4 = dinv2[e1.x], w5 = dinv2[e1.y], w6 = dinv2[e1.z], w7 = dinv2[e1.w];
            fma4(a0, w0, h4[(size_t)e0.x * 8 + f4]);
            fma4(a1, w1, h4[(size_t)e0.y * 8 + f4]);
            fma4(a2, w2, h4[(size_t)e0.z * 8 + f4]);
            fma4(a3, w3, h4[(size_t)e0.w * 8 + f4]);
            fma4(a0, w4, h4[(size_t)e1.x * 8 + f4]);
            fma4(a1, w5, h4[(size_t)e1.y * 8 + f4]);
            fma4(a2, w6, h4[(size_t)e1.z * 8 + f4]);
            fma4(a3, w7, h4[(size_t)e1.w * 8 + f4]);
        }
        if (j + 4 <= m) {
            int4 e0 = *(const int4*)(eidx + beg + j);
            fma4(a0, dinv2[e0.x], h4[(size_t)e0.x * 8 + f4]);
            fma4(a1, dinv2[e0.y], h4[(size_t)e0.y * 8 + f4]);
            fma4(a2, dinv2[e0.z], h4[(size_t)e0.z * 8 + f4]);
            fma4(a3, dinv2[e0.w], h4[(size_t)e0.w * 8 + f4]);
            j += 4;
        }
        for (; j < m; ++j) {
            int s = eidx[beg + j];
            fma4(a0, dinv2[s], h4[(size_t)s * 8 + f4]);
        }
        add4(a0, a1); add4(a2, a3); add4(a0, a2);
        float di = dinv2[node];
        float4 self = h4[(size_t)node * 8 + f4];
        float4 bv = ((const float4*)b2)[f4];
        float4 o;
        o.x = di * (a0.x + di * self.x) + bv.x;
        o.y = di * (a0.y + di * self.y) + bv.y;
        o.z = di * (a0.z + di * self.z) + bv.z;
        o.w = di * (a0.w + di * self.w) + bv.w;
        o.x = o.x > 0.f ? o.x : 0.f;
        o.y = o.y > 0.f ? o.y : 0.f;
        o.z = o.z > 0.f ? o.z : 0.f;
        o.w = o.w > 0.f ? o.w : 0.f;
        *(float4*)&xs[ln * 36 + f4 * 4] = o;   // x2 row, LDS only
    }
    __syncthreads();
    if (node < n) {
        const int c0 = f4 * 2;
        float s0 = 0.f, s1 = 0.f;
#pragma unroll
        for (int k = 0; k < 32; ++k) {
            float xv = xs[ln * 36 + k];
            s0 += xv * W3s[k * 16 + c0];
            s1 += xv * W3s[k * 16 + c0 + 1];
        }
        ((float2*)h3)[(size_t)node * 8 + f4] = make_float2(s0, s1);   // raw h3
    }
}

// K5: gather3 -> out. 256 thr = 64 nodes x 4 lanes.
__global__ void __launch_bounds__(256) k5_gather3(
        const int* __restrict__ row_ptr3, const int* __restrict__ cnt3,
        const int* __restrict__ eidx, const float* __restrict__ dinv3,
        const float* __restrict__ h3, const float* __restrict__ b3,
        float* __restrict__ out, int n) {
    const int ln = threadIdx.x >> 2;
    const int f4 = threadIdx.x & 3;
    const int node = blockIdx.x * 64 + ln;
    if (node >= n) return;
    const int beg = row_ptr3[node];
    const int m = cnt3[node];
    const float4* h4 = (const float4*)h3;
    float4 a0 = make_float4(0.f, 0.f, 0.f, 0.f), a1 = a0, a2 = a0, a3 = a0;
    int j = 0;
    for (; j + 8 <= m; j += 8) {
        int4 e0 = *(const int4*)(eidx + beg + j);
        int4 e1 = *(const int4*)(eidx + beg + j + 4);
        float w0 = dinv3[e0.x], w1 = dinv3[e0.y], w2 = dinv3[e0.z], w3 = dinv3[e0.w];
        float w4 = dinv3[e1.x], w5 = dinv3[e1.y], w6 = dinv3[e1.z], w7 = dinv3[e1.w];
        fma4(a0, w0, h4[(size_t)e0.x * 4 + f4]);
        fma4(a1, w1, h4[(size_t)e0.y * 4 + f4]);
        fma4(a2, w2, h4[(size_t)e0.z * 4 + f4]);
        fma4(a3, w3, h4[(size_t)e0.w * 4 + f4]);
        fma4(a0, w4, h4[(size_t)e1.x * 4 + f4]);
        fma4(a1, w5, h4[(size_t)e1.y * 4 + f4]);
        fma4(a2, w6, h4[(size_t)e1.z * 4 + f4]);
        fma4(a3, w7, h4[(size_t)e1.w * 4 + f4]);
    }
    if (j + 4 <= m) {
        int4 e0 = *(const int4*)(eidx + beg + j);
        fma4(a0, dinv3[e0.x], h4[(size_t)e0.x * 4 + f4]);
        fma4(a1, dinv3[e0.y], h4[(size_t)e0.y * 4 + f4]);
        fma4(a2, dinv3[e0.z], h4[(size_t)e0.z * 4 + f4]);
        fma4(a3, dinv3[e0.w], h4[(size_t)e0.w * 4 + f4]);
        j += 4;
    }
    for (; j < m; ++j) {
        int s = eidx[beg + j];
        fma4(a0, dinv3[s], h4[(size_t)s * 4 + f4]);
    }
    add4(a0, a1); add4(a2, a3); add4(a0, a2);
    float di = dinv3[node];
    float4 self = h4[(size_t)node * 4 + f4];
    float4 bv = ((const float4*)b3)[f4];
    float4 o;
    o.x = di * (a0.x + di * self.x) + bv.x;
    o.y = di * (a0.y + di * self.y) + bv.y;
    o.z = di * (a0.z + di * self.z) + bv.z;
    o.w = di * (a0.w + di * self.w) + bv.w;
    o.x = o.x > 0.f ? o.x : 0.f;
    o.y = o.y > 0.f ? o.y : 0.f;
    o.z = o.z > 0.f ? o.z : 0.f;
    o.w = o.w > 0.f ? o.w : 0.f;
    ((float4*)out)[(size_t)node * 4 + f4] = o;
}

extern "C" void kernel_launch(void* const* d_in, const int* in_sizes, int n_in,
                              void* d_out, int out_size, void* d_ws, size_t ws_size,
                              hipStream_t stream) {
    const float* x0  = (const float*)d_in[0];
    const int*   ei1 = (const int*)d_in[1];
    const int*   ei3 = (const int*)d_in[2];
    const int*   ei9 = (const int*)d_in[3];
    const float* W1  = (const float*)d_in[4];
    const float* b1  = (const float*)d_in[5];
    const float* W2  = (const float*)d_in[6];
    const float* b2  = (const float*)d_in[7];
    const float* W3  = (const float*)d_in[8];
    const float* b3  = (const float*)d_in[9];

    const int n  = in_sizes[0] / 64;  // 50000
    const int E1 = in_sizes[1] / 2;   // 800000
    const int E3 = in_sizes[2] / 2;
    const int E9 = in_sizes[3] / 2;
    const int n3 = 3 * n;
    const int W  = (n + NB - 1) / NB; // 196 (< 512 -> 9-bit local id)

    const int nc1 = (E1 + CH - 1) / CH;
    const int nc2 = (E3 + CH - 1) / CH;
    const int nc3 = (E9 + CH - 1) / CH;
    const int nchunks = nc1 + nc2 + nc3;

    int* gcur    = (int*)d_ws;                           // TB
    unsigned int* pairBuf = (unsigned int*)(gcur + TB);  // TB*CAPE
    int* eidx    = (int*)(pairBuf + (size_t)TB * CAPE);  // TB*CAPE
    int* row_ptr = eidx + (size_t)TB * CAPE;             // 3n
    int* cnt     = row_ptr + n3;                         // 3n
    float* dinv  = (float*)(cnt + n3);                   // 3n
    float* h1    = dinv + n3;                            // n*64
    float* h2    = h1 + (size_t)n * 64;                  // n*32
    float* h3    = h2 + (size_t)n * 32;                  // n*16

    hipMemsetAsync(gcur, 0, TB * sizeof(int), stream);
    phase1<<<nchunks, P1T, 0, stream>>>(ei1, ei1 + E1, E1, ei3, ei3 + E3, E3,
                                        ei9, ei9 + E9, E9, nc1, nc2, W, gcur, pairBuf);
    gemm1_raw<<<(n + 63) / 64, 256, 0, stream>>>(x0, W1, h1, n);
    phase2<<<TB, P2T, 0, stream>>>(pairBuf, gcur, n, W, row_ptr, cnt, dinv, eidx);
    k3_gather1_gemm2<<<(n + 15) / 16, 256, 0, stream>>>(
        row_ptr, cnt, eidx, dinv, h1, b1, W2, h2, n);
    k4_gather2_gemm3<<<(n + 31) / 32, 256, 0, stream>>>(
        row_ptr + n, cnt + n, eidx, dinv + n, h2, b2, W3, h3, n);
    k5_gather3<<<(n + 63) / 64, 256, 0, stream>>>(
        row_ptr + 2 * n, cnt + 2 * n, eidx, dinv + 2 * n, h3, b3, (float*)d_out, n);
}

// Round 11
// 201.084 us; speedup vs baseline: 1.3921x; 1.0119x over previous
//
#include <hip/hip_runtime.h>

// ---------------------------------------------------------------------------
// 3-layer GCN, 5 dispatches:
//  K1: phase1 bucket-sort (counting sort into per-bucket arena, dense writes)
//  K2: [phase2 per-bucket node sort -> row_ptr/cnt/dinv + u16 eidx (768 wgs)]
//      ∥ [raw gemm1 h1 = x0 @ W1 (391 wgs)]  — safe to co-schedule: phase2's
//      global writes are dense full-line bursts, unlike phase1's (R8).
//  K3: gather1 (per-edge FMA with dinv1[s]) + fused gemm2 -> h2 = x1@W2
//  K4: gather2 + fused gemm3 -> h3 = x2@W3
//  K5: gather3 -> out
// x1/x2 live only in LDS. eidx is uint16 (src < 65536) — halves index traffic.
// NOTE (R6): f32 LDS atomicAdd is a serializing slow path on gfx950 — int
// LDS atomics are fast. Never aggregate floats through LDS atomics.
// NOTE (R7): gather is LLC-bandwidth-bound (~8 XCDs x |h| compulsory);
// unroll deeper than 8 is neutral.
// NOTE (R8): never co-schedule streaming traffic with phase1's L2-resident
// 4B scatter — partial dirty lines get evicted -> 10x write amplification.
// ---------------------------------------------------------------------------

#define NB   256            // buckets per layer (W = ceil(n/NB) = 196 < 512)
#define NL   3
#define TB   (NB * NL)      // 768 buckets
#define CAPE 6400           // arena capacity per bucket (mean fill ~3125)
#define CAPE_E (CAPE + 8)   // u16 eidx arena stride (+8 spill room for int4 copy)
#define CH   8192           // edges per phase-1 chunk
#define P1T  512
#define EPT  (CH / P1T)     // 16 edges per thread, in registers
#define P2T  512

__device__ __forceinline__ void decode_chunk(int g, int nc1, int nc2,
                                             const int* s1, const int* d1, int E1,
                                             const int* s2, const int* d2, int E2,
                                             const int* s3, const int* d3, int E3,
                                             const int** src, const int** dst, int* E, int* l,
                                             int* gout) {
    if (g < nc1)            { *src = s1; *dst = d1; *E = E1; *l = 0; }
    else if (g < nc1 + nc2) { *src = s2; *dst = d2; *E = E2; *l = 1; g -= nc1; }
    else                    { *src = s3; *dst = d3; *E = E3; *l = 2; g -= nc1 + nc2; }
    *gout = g;
}

__device__ __forceinline__ void fma4(float4& a, float s, const float4& w) {
    a.x += s * w.x; a.y += s * w.y; a.z += s * w.z; a.w += s * w.w;
}
__device__ __forceinline__ void add4(float4& a, const float4& v) {
    a.x += v.x; a.y += v.y; a.z += v.z; a.w += v.w;
}

__global__ void __launch_bounds__(P1T) phase1(
        const int* __restrict__ s1, const int* __restrict__ d1, int E1,
        const int* __restrict__ s2, const int* __restrict__ d2, int E2,
        const int* __restrict__ s3, const int* __restrict__ d3, int E3,
        int nc1, int nc2, int W,
        int* __restrict__ gcur, unsigned int* __restrict__ pairBuf) {
    __shared__ int hist[TB];
    __shared__ int bo[TB];
    __shared__ int lcur[TB];
    for (int i = threadIdx.x; i < TB; i += P1T) hist[i] = 0;
    __syncthreads();
    const int* src; const int* dst; int E, l, g;
    decode_chunk(blockIdx.x, nc1, nc2, s1, d1, E1, s2, d2, E2, s3, d3, E3,
                 &src, &dst, &E, &l, &g);
    const int e0 = g * CH;
    const int lbase = l * NB;
    unsigned pv[EPT];
    int bn[EPT];
    if (E - e0 >= CH) {                       // full chunk: int4 register loads
        const int4* s4 = (const int4*)(src + e0);
        const int4* d4 = (const int4*)(dst + e0);
#pragma unroll
        for (int w = 0; w < EPT / 4; ++w) {
            int4 sv = s4[threadIdx.x + w * P1T];
            int4 dv = d4[threadIdx.x + w * P1T];
            int q, i = w * 4;
            q = dv.x / W; bn[i+0] = lbase + q; pv[i+0] = ((unsigned)sv.x << 9) | (unsigned)(dv.x - q * W);
            q = dv.y / W; bn[i+1] = lbase + q; pv[i+1] = ((unsigned)sv.y << 9) | (unsigned)(dv.y - q * W);
            q = dv.z / W; bn[i+2] = lbase + q; pv[i+2] = ((unsigned)sv.z << 9) | (unsigned)(dv.z - q * W);
            q = dv.w / W; bn[i+3] = lbase + q; pv[i+3] = ((unsigned)sv.w << 9) | (unsigned)(dv.w - q * W);
        }
    } else {                                   // tail chunk: guarded scalar loads
#pragma unroll
        for (int i = 0; i < EPT; ++i) {
            int e = e0 + threadIdx.x + i * P1T;
            if (e < E) {
                int s = src[e], d = dst[e];
                int q = d / W;
                bn[i] = lbase + q;
                pv[i] = ((unsigned)s << 9) | (unsigned)(d - q * W);
            } else bn[i] = -1;
        }
    }
#pragma unroll
    for (int i = 0; i < EPT; ++i)
        if (bn[i] >= 0) atomicAdd(&hist[bn[i]], 1);
    __syncthreads();
    for (int i = threadIdx.x; i < TB; i += P1T) {
        int c = hist[i];
        bo[i] = i * CAPE + (c ? atomicAdd(&gcur[i], c) : 0);
        lcur[i] = 0;
    }
    __syncthreads();
#pragma unroll
    for (int i = 0; i < EPT; ++i) {
        if (bn[i] >= 0) {
            int r = atomicAdd(&lcur[bn[i]], 1);
            int pos = bo[bn[i]] + r;
            if (pos < (bn[i] + 1) * CAPE) pairBuf[pos] = pv[i];  // overflow guard
        }
    }
}

// K2: blocks [0,TB) = phase2 (per-bucket node sort, u16 eidx); blocks
// [TB, TB+gemmBlks) = raw gemm1 (h1 = x0 @ W1, 128 rows/block).
__global__ void __launch_bounds__(P2T) k2_phase2_gemm1(
        const unsigned int* __restrict__ pairBuf, const int* __restrict__ gcur,
        int n, int W,
        int* __restrict__ row_ptr, int* __restrict__ cnt_g,
        float* __restrict__ dinv, unsigned short* __restrict__ eidx,
        const float* __restrict__ x0, const float* __restrict__ W1g,
        float* __restrict__ h1) {
    __shared__ __align__(16) char smem[17408];   // max(phase2 ~16.9KB, gemm 16KB)
    if (blockIdx.x < (unsigned)TB) {
        int* lcnt  = (int*)smem;                           // P2T ints
        int* lscan = lcnt + P2T;                           // P2T ints
        unsigned short* stage = (unsigned short*)(lscan + P2T);  // CAPE+8 u16
        const int bid = blockIdx.x;
        const int l = bid / NB, k = bid % NB;
        const int lo = k * W;
        const int hi = min(n, lo + W);
        const int Wn = hi - lo;                 // <= 196 < P2T
        const int segE = min(gcur[bid], CAPE);
        const size_t base  = (size_t)bid * CAPE;     // pairBuf (u32) arena
        const int    baseE = bid * CAPE_E;           // eidx (u16) arena
        const int t = threadIdx.x;
        lcnt[t] = 0;
        __syncthreads();
        for (int i = t; i < segE; i += P2T)
            atomicAdd(&lcnt[pairBuf[base + i] & 511u], 1);
        __syncthreads();
        const int v = lcnt[t];
        const int vp = (v + 3) & ~3;            // pad segments to x4
        lscan[t] = vp;
        __syncthreads();
        for (int off = 1; off < P2T; off <<= 1) {
            int add = (t >= off) ? lscan[t - off] : 0;
            __syncthreads();
            lscan[t] += add;
            __syncthreads();
        }
        const int pexcl = lscan[t] - vp;
        const int segEp = lscan[P2T - 1];
        if (t < Wn) {
            int node = l * n + lo + t;
            row_ptr[node] = baseE + pexcl;      // u16 units; both %4 == 0
            cnt_g[node] = v;
            dinv[node] = rsqrtf((float)v + 1.0f);   // +1 self-loop
        }
        __syncthreads();
        lcnt[t] = pexcl;
        __syncthreads();
        const bool lds_ok = (segEp <= CAPE);
        for (int i = t; i < segE; i += P2T) {
            unsigned p = pairBuf[base + i];
            int pos = atomicAdd(&lcnt[p & 511u], 1);
            unsigned short s = (unsigned short)(p >> 9);
            if (lds_ok) stage[pos] = s;
            else if (pos < CAPE_E) eidx[baseE + pos] = s;
        }
        __syncthreads();
        if (lds_ok) {
            const int4* st4 = (const int4*)stage;
            int4* e4 = (int4*)(eidx + baseE);
            int m16 = (segEp + 7) >> 3;         // 16B chunks of 8 u16
            for (int i = t; i < m16; i += P2T) e4[i] = st4[i];  // spill < +8 ok
        }
    } else {
        // raw gemm1: 512 thr, TC=16 float4-cols x TR=32 rows, RPT=4 -> BR=128
        float* Ws = (float*)smem;               // 16 KB
        const int bid = blockIdx.x - TB;
        for (int i = threadIdx.x; i < 1024; i += P2T)
            ((float4*)Ws)[i] = ((const float4*)W1g)[i];
        __syncthreads();
        const int tc = threadIdx.x % 16;
        const int tr = threadIdx.x / 16;
        const int row0 = bid * 128 + tr * 4;
        const float4* x4 = (const float4*)x0;
        const float4* Ws4 = (const float4*)Ws;
        float4 acc[4];
#pragma unroll
        for (int r = 0; r < 4; ++r) acc[r] = make_float4(0.f, 0.f, 0.f, 0.f);
        int rowc[4];
#pragma unroll
        for (int r = 0; r < 4; ++r) rowc[r] = min(row0 + r, n - 1);
        for (int k0 = 0; k0 < 64; k0 += 4) {
            float4 wv0 = Ws4[(k0 + 0) * 16 + tc];
            float4 wv1 = Ws4[(k0 + 1) * 16 + tc];
            float4 wv2 = Ws4[(k0 + 2) * 16 + tc];
            float4 wv3 = Ws4[(k0 + 3) * 16 + tc];
#pragma unroll
            for (int r = 0; r < 4; ++r) {
                float4 xv = x4[(size_t)rowc[r] * 16 + (k0 / 4)];
                fma4(acc[r], xv.x, wv0);
                fma4(acc[r], xv.y, wv1);
                fma4(acc[r], xv.z, wv2);
                fma4(acc[r], xv.w, wv3);
            }
        }
        float4* h4 = (float4*)h1;
#pragma unroll
        for (int r = 0; r < 4; ++r) {
            int row = row0 + r;
            if (row < n) h4[(size_t)row * 16 + tc] = acc[r];
        }
    }
}

// K3: gather1 (dinv-weighted FMA over raw h1 rows) + fused gemm2.
// 256 thr = 16 nodes x 16 lanes; x1 row staged in LDS, never global.
__global__ void __launch_bounds__(256) k3_gather1_gemm2(
        const int* __restrict__ row_ptr, const int* __restrict__ cnt,
        const unsigned short* __restrict__ eidx, const float* __restrict__ dinv1,
        const float* __restrict__ h1, const float* __restrict__ b1,
        const float* __restrict__ W2g, float* __restrict__ h2, int n) {
    __shared__ float xs[16 * 68];    // 16 nodes x 64 feats, pad 68
    __shared__ float W2s[64 * 32];   // 8 KB
    for (int i = threadIdx.x; i < 512; i += 256)
        ((float4*)W2s)[i] = ((const float4*)W2g)[i];
    const int ln = threadIdx.x >> 4;
    const int f4 = threadIdx.x & 15;
    const int node = blockIdx.x * 16 + ln;
    if (node < n) {
        const int beg = row_ptr[node];          // u16 units, multiple of 4
        const int m = cnt[node];
        const float4* h4 = (const float4*)h1;
        float4 a0 = make_float4(0.f, 0.f, 0.f, 0.f), a1 = a0, a2 = a0, a3 = a0;
        int j = 0;
        for (; j + 8 <= m; j += 8) {
            ushort4 e0 = *(const ushort4*)(eidx + beg + j);
            ushort4 e1 = *(const ushort4*)(eidx + beg + j + 4);
            float w0 = dinv1[e0.x], w1 = dinv1[e0.y], w2 = dinv1[e0.z], w3 = dinv1[e0.w];
            float w4 = dinv1[e1.x], w5 = dinv1[e1.y], w6 = dinv1[e1.z], w7 = dinv1[e1.w];
            float4 v0 = h4[(size_t)e0.x * 16 + f4];
            float4 v1 = h4[(size_t)e0.y * 16 + f4];
            float4 v2 = h4[(size_t)e0.z * 16 + f4];
            float4 v3 = h4[(size_t)e0.w * 16 + f4];
            float4 v4 = h4[(size_t)e1.x * 16 + f4];
            float4 v5 = h4[(size_t)e1.y * 16 + f4];
            float4 v6 = h4[(size_t)e1.z * 16 + f4];
            float4 v7 = h4[(size_t)e1.w * 16 + f4];
            fma4(a0, w0, v0); fma4(a1, w1, v1); fma4(a2, w2, v2); fma4(a3, w3, v3);
            fma4(a0, w4, v4); fma4(a1, w5, v5); fma4(a2, w6, v6); fma4(a3, w7, v7);
        }
        if (j + 4 <= m) {
            ushort4 e0 = *(const ushort4*)(eidx + beg + j);
            fma4(a0, dinv1[e0.x], h4[(size_t)e0.x * 16 + f4]);
            fma4(a1, dinv1[e0.y], h4[(size_t)e0.y * 16 + f4]);
            fma4(a2, dinv1[e0.z], h4[(size_t)e0.z * 16 + f4]);
            fma4(a3, dinv1[e0.w], h4[(size_t)e0.w * 16 + f4]);
            j += 4;
        }
        for (; j < m; ++j) {
            int s = eidx[beg + j];
            fma4(a0, dinv1[s], h4[(size_t)s * 16 + f4]);
        }
        add4(a0, a1); add4(a2, a3); add4(a0, a2);
        float di = dinv1[node];
        float4 self = h4[(size_t)node * 16 + f4];
        float4 bv = ((const float4*)b1)[f4];
        float4 o;
        o.x = di * (a0.x + di * self.x) + bv.x;
        o.y = di * (a0.y + di * self.y) + bv.y;
        o.z = di * (a0.z + di * self.z) + bv.z;
        o.w = di * (a0.w + di * self.w) + bv.w;
        o.x = o.x > 0.f ? o.x : 0.f;
        o.y = o.y > 0.f ? o.y : 0.f;
        o.z = o.z > 0.f ? o.z : 0.f;
        o.w = o.w > 0.f ? o.w : 0.f;
        *(float4*)&xs[ln * 68 + f4 * 4] = o;   // x1 row, LDS only
    }
    __syncthreads();
    if (node < n) {
        const int c0 = f4 * 2;
        float s0 = 0.f, s1 = 0.f;
#pragma unroll
        for (int k = 0; k < 64; ++k) {
            float xv = xs[ln * 68 + k];
            s0 += xv * W2s[k * 32 + c0];
            s1 += xv * W2s[k * 32 + c0 + 1];
        }
        ((float2*)h2)[(size_t)node * 16 + f4] = make_float2(s0, s1);  // raw h2
    }
}

// K4: gather2 + fused gemm3. 256 thr = 32 nodes x 8 lanes.
__global__ void __launch_bounds__(256) k4_gather2_gemm3(
        const int* __restrict__ row_ptr2, const int* __restrict__ cnt2,
        const unsigned short* __restrict__ eidx, const float* __restrict__ dinv2,
        const float* __restrict__ h2, const float* __restrict__ b2,
        const float* __restrict__ W3g, float* __restrict__ h3, int n) {
    __shared__ float xs[32 * 36];    // 32 nodes x 32 feats, pad 36
    __shared__ float W3s[32 * 16];   // 2 KB
    for (int i = threadIdx.x; i < 128; i += 256)
        ((float4*)W3s)[i] = ((const float4*)W3g)[i];
    const int ln = threadIdx.x >> 3;
    const int f4 = threadIdx.x & 7;
    const int node = blockIdx.x * 32 + ln;
    if (node < n) {
        const int beg = row_ptr2[node];
        const int m = cnt2[node];
        const float4* h4 = (const float4*)h2;
        float4 a0 = make_float4(0.f, 0.f, 0.f, 0.f), a1 = a0, a2 = a0, a3 = a0;
        int j = 0;
        for (; j + 8 <= m; j += 8) {
            ushort4 e0 = *(const ushort4*)(eidx + beg + j);
            ushort4 e1 = *(const ushort4*)(eidx + beg + j + 4);
            float w0 = dinv2[e0.x], w1 = dinv2[e0.y], w2 = dinv2[e0.z], w3 = dinv2[e0.w];
            float w4 = dinv2[e1.x], w5 = dinv2[e1.y], w6 = dinv2[e1.z], w7 = dinv2[e1.w];
            fma4(a0, w0, h4[(size_t)e0.x * 8 + f4]);
            fma4(a1, w1, h4[(size_t)e0.y * 8 + f4]);
            fma4(a2, w2, h4[(size_t)e0.z * 8 + f4]);
            fma4(a3, w3, h4[(size_t)e0.w * 8 + f4]);
            fma4(a0, w4, h4[(size_t)e1.x * 8 + f4]);
            fma4(a1, w5, h4[(size_t)e1.y * 8 + f4]);
            fma4(a2, w6, h4[(size_t)e1.z * 8 + f4]);
            fma4(a3, w7, h4[(size_t)e1.w * 8 + f4]);
        }
        if (j + 4 <= m) {
            ushort4 e0 = *(const ushort4*)(eidx + beg + j);
            fma4(a0, dinv2[e0.x], h4[(size_t)e0.x * 8 + f4]);
            fma4(a1, dinv2[e0.y], h4[(size_t)e0.y * 8 + f4]);
            fma4(a2, dinv2[e0.z], h4[(size_t)e0.z * 8 + f4]);
            fma4(a3, dinv2[e0.w], h4[(size_t)e0.w * 8 + f4]);
            j += 4;
        }
        for (; j < m; ++j) {
            int s = eidx[beg + j];
            fma4(a0, dinv2[s], h4[(size_t)s * 8 + f4]);
        }
        add4(a0, a1); add4(a2, a3); add4(a0, a2);
        float di = dinv2[node];
        float4 self = h4[(size_t)node * 8 + f4];
        float4 bv = ((const float4*)b2)[f4];
        float4 o;
        o.x = di * (a0.x + di * self.x) + bv.x;
        o.y = di * (a0.y + di * self.y) + bv.y;
        o.z = di * (a0.z + di * self.z) + bv.z;
        o.w = di * (a0.w + di * self.w) + bv.w;
        o.x = o.x > 0.f ? o.x : 0.f;
        o.y = o.y > 0.f ? o.y : 0.f;
        o.z = o.z > 0.f ? o.z : 0.f;
        o.w = o.w > 0.f ? o.w : 0.f;
        *(float4*)&xs[ln * 36 + f4 * 4] = o;   // x2 row, LDS only
    }
    __syncthreads();
    if (node < n) {
        const int c0 = f4 * 2;
        float s0 = 0.f, s1 = 0.f;
#pragma unroll
        for (int k = 0; k < 32; ++k) {
            float xv = xs[ln * 36 + k];
            s0 += xv * W3s[k * 16 + c0];
            s1 += xv * W3s[k * 16 + c0 + 1];
        }
        ((float2*)h3)[(size_t)node * 8 + f4] = make_float2(s0, s1);   // raw h3
    }
}

// K5: gather3 -> out. 256 thr = 64 nodes x 4 lanes.
__global__ void __launch_bounds__(256) k5_gather3(
        const int* __restrict__ row_ptr3, const int* __restrict__ cnt3,
        const unsigned short* __restrict__ eidx, const float* __restrict__ dinv3,
        const float* __restrict__ h3, const float* __restrict__ b3,
        float* __restrict__ out, int n) {
    const int ln = threadIdx.x >> 2;
    const int f4 = threadIdx.x & 3;
    const int node = blockIdx.x * 64 + ln;
    if (node >= n) return;
    const int beg = row_ptr3[node];
    const int m = cnt3[node];
    const float4* h4 = (const float4*)h3;
    float4 a0 = make_float4(0.f, 0.f, 0.f, 0.f), a1 = a0, a2 = a0, a3 = a0;
    int j = 0;
    for (; j + 8 <= m; j += 8) {
        ushort4 e0 = *(const ushort4*)(eidx + beg + j);
        ushort4 e1 = *(const ushort4*)(eidx + beg + j + 4);
        float w0 = dinv3[e0.x], w1 = dinv3[e0.y], w2 = dinv3[e0.z], w3 = dinv3[e0.w];
        float w4 = dinv3[e1.x], w5 = dinv3[e1.y], w6 = dinv3[e1.z], w7 = dinv3[e1.w];
        fma4(a0, w0, h4[(size_t)e0.x * 4 + f4]);
        fma4(a1, w1, h4[(size_t)e0.y * 4 + f4]);
        fma4(a2, w2, h4[(size_t)e0.z * 4 + f4]);
        fma4(a3, w3, h4[(size_t)e0.w * 4 + f4]);
        fma4(a0, w4, h4[(size_t)e1.x * 4 + f4]);
        fma4(a1, w5, h4[(size_t)e1.y * 4 + f4]);
        fma4(a2, w6, h4[(size_t)e1.z * 4 + f4]);
        fma4(a3, w7, h4[(size_t)e1.w * 4 + f4]);
    }
    if (j + 4 <= m) {
        ushort4 e0 = *(const ushort4*)(eidx + beg + j);
        fma4(a0, dinv3[e0.x], h4[(size_t)e0.x * 4 + f4]);
        fma4(a1, dinv3[e0.y], h4[(size_t)e0.y * 4 + f4]);
        fma4(a2, dinv3[e0.z], h4[(size_t)e0.z * 4 + f4]);
        fma4(a3, dinv3[e0.w], h4[(size_t)e0.w * 4 + f4]);
        j += 4;
    }
    for (; j < m; ++j) {
        int s = eidx[beg + j];
        fma4(a0, dinv3[s], h4[(size_t)s * 4 + f4]);
    }
    add4(a0, a1); add4(a2, a3); add4(a0, a2);
    float di = dinv3[node];
    float4 self = h4[(size_t)node * 4 + f4];
    float4 bv = ((const float4*)b3)[f4];
    float4 o;
    o.x = di * (a0.x + di * self.x) + bv.x;
    o.y = di * (a0.y + di * self.y) + bv.y;
    o.z = di * (a0.z + di * self.z) + bv.z;
    o.w = di * (a0.w + di * self.w) + bv.w;
    o.x = o.x > 0.f ? o.x : 0.f;
    o.y = o.y > 0.f ? o.y : 0.f;
    o.z = o.z > 0.f ? o.z : 0.f;
    o.w = o.w > 0.f ? o.w : 0.f;
    ((float4*)out)[(size_t)node * 4 + f4] = o;
}

extern "C" void kernel_launch(void* const* d_in, const int* in_sizes, int n_in,
                              void* d_out, int out_size, void* d_ws, size_t ws_size,
                              hipStream_t stream) {
    const float* x0  = (const float*)d_in[0];
    const int*   ei1 = (const int*)d_in[1];
    const int*   ei3 = (const int*)d_in[2];
    const int*   ei9 = (const int*)d_in[3];
    const float* W1  = (const float*)d_in[4];
    const float* b1  = (const float*)d_in[5];
    const float* W2  = (const float*)d_in[6];
    const float* b2  = (const float*)d_in[7];
    const float* W3  = (const float*)d_in[8];
    const float* b3  = (const float*)d_in[9];

    const int n  = in_sizes[0] / 64;  // 50000
    const int E1 = in_sizes[1] / 2;   // 800000
    const int E3 = in_sizes[2] / 2;
    const int E9 = in_sizes[3] / 2;
    const int n3 = 3 * n;
    const int W  = (n + NB - 1) / NB; // 196 (< 512 -> 9-bit local id)

    const int nc1 = (E1 + CH - 1) / CH;
    const int nc2 = (E3 + CH - 1) / CH;
    const int nc3 = (E9 + CH - 1) / CH;
    const int nchunks = nc1 + nc2 + nc3;
    const int gemmBlks = (n + 127) / 128;

    int* gcur    = (int*)d_ws;                           // TB
    unsigned int* pairBuf = (unsigned int*)(gcur + TB);  // TB*CAPE u32
    unsigned short* eidx = (unsigned short*)(pairBuf + (size_t)TB * CAPE); // TB*CAPE_E u16
    int* row_ptr = (int*)(eidx + (size_t)TB * CAPE_E);   // 3n
    int* cnt     = row_ptr + n3;                         // 3n
    float* dinv  = (float*)(cnt + n3);                   // 3n
    float* h1    = dinv + n3;                            // n*64
    float* h2    = h1 + (size_t)n * 64;                  // n*32
    float* h3    = h2 + (size_t)n * 32;                  // n*16

    hipMemsetAsync(gcur, 0, TB * sizeof(int), stream);
    phase1<<<nchunks, P1T, 0, stream>>>(ei1, ei1 + E1, E1, ei3, ei3 + E3, E3,
                                        ei9, ei9 + E9, E9, nc1, nc2, W, gcur, pairBuf);
    k2_phase2_gemm1<<<TB + gemmBlks, P2T, 0, stream>>>(
        pairBuf, gcur, n, W, row_ptr, cnt, dinv, eidx, x0, W1, h1);
    k3_gather1_gemm2<<<(n + 15) / 16, 256, 0, stream>>>(
        row_ptr, cnt, eidx, dinv, h1, b1, W2, h2, n);
    k4_gather2_gemm3<<<(n + 31) / 32, 256, 0, stream>>>(
        row_ptr + n, cnt + n, eidx, dinv + n, h2, b2, W3, h3, n);
    k5_gather3<<<(n + 63) / 64, 256, 0, stream>>>(
        row_ptr + 2 * n, cnt + 2 * n, eidx, dinv + 2 * n, h3, b3, (float*)d_out, n);
}

// Round 12
// 181.591 us; speedup vs baseline: 1.5415x; 1.1073x over previous
//
#include <hip/hip_runtime.h>
#include <hip/hip_fp16.h>

// ---------------------------------------------------------------------------
// 3-layer GCN, 5 dispatches:
//  K1: phase1 bucket-sort (counting sort into per-bucket arena, dense writes)
//  K2: [phase2 per-bucket node sort -> row_ptr/cnt/dinv + u16 eidx (768 wgs)]
//      ∥ [raw gemm1 h1 = x0 @ W1 (rest)]
//  K3: gather1 (per-edge FMA with dinv1[s]) + fused gemm2 -> h2 = x1@W2
//  K4: gather2 + fused gemm3 -> h3 = x2@W3
//  K5: gather3 -> out
// h1/h2/h3 stored FP16 (accumulate fp32): gathers are LLC-BW-bound at
// ~8 XCDs x |h| compulsory traffic (R7/R10) — halving bytes halves the floor.
// x1/x2 live only in LDS. eidx is uint16.
// NOTE (R6): f32 LDS atomicAdd is a serializing slow path on gfx950.
// NOTE (R8): never co-schedule streaming traffic with phase1's 4B scatter.
// ---------------------------------------------------------------------------

#define NB   256            // buckets per layer (W = ceil(n/NB) = 196 < 512)
#define NL   3
#define TB   (NB * NL)      // 768 buckets
#define CAPE 6400           // arena capacity per bucket (mean fill ~3125)
#define CAPE_E (CAPE + 8)   // u16 eidx arena stride (+8 spill room)
#define CH   8192           // edges per phase-1 chunk
#define P1T  512
#define EPT  (CH / P1T)
#define P2T  512

__device__ __forceinline__ void decode_chunk(int g, int nc1, int nc2,
                                             const int* s1, const int* d1, int E1,
                                             const int* s2, const int* d2, int E2,
                                             const int* s3, const int* d3, int E3,
                                             const int** src, const int** dst, int* E, int* l,
                                             int* gout) {
    if (g < nc1)            { *src = s1; *dst = d1; *E = E1; *l = 0; }
    else if (g < nc1 + nc2) { *src = s2; *dst = d2; *E = E2; *l = 1; g -= nc1; }
    else                    { *src = s3; *dst = d3; *E = E3; *l = 2; g -= nc1 + nc2; }
    *gout = g;
}

__device__ __forceinline__ void fma4(float4& a, float s, const float4& w) {
    a.x += s * w.x; a.y += s * w.y; a.z += s * w.z; a.w += s * w.w;
}
__device__ __forceinline__ void add4(float4& a, const float4& v) {
    a.x += v.x; a.y += v.y; a.z += v.z; a.w += v.w;
}
// load 4 fp16 (8 B) at index idx4 (units of 4 halves) -> float4
__device__ __forceinline__ float4 ldh4(const __half* h, size_t idx4) {
    uint2 r = ((const uint2*)h)[idx4];
    __half2 a = *reinterpret_cast<__half2*>(&r.x);
    __half2 b = *reinterpret_cast<__half2*>(&r.y);
    float2 fa = __half22float2(a), fb = __half22float2(b);
    return make_float4(fa.x, fa.y, fb.x, fb.y);
}
__device__ __forceinline__ void sth4(__half* h, size_t idx4, float4 v) {
    __half2 a = __floats2half2_rn(v.x, v.y);
    __half2 b = __floats2half2_rn(v.z, v.w);
    uint2 r;
    r.x = *reinterpret_cast<unsigned*>(&a);
    r.y = *reinterpret_cast<unsigned*>(&b);
    ((uint2*)h)[idx4] = r;
}

__global__ void __launch_bounds__(P1T) phase1(
        const int* __restrict__ s1, const int* __restrict__ d1, int E1,
        const int* __restrict__ s2, const int* __restrict__ d2, int E2,
        const int* __restrict__ s3, const int* __restrict__ d3, int E3,
        int nc1, int nc2, int W,
        int* __restrict__ gcur, unsigned int* __restrict__ pairBuf) {
    __shared__ int hist[TB];
    __shared__ int bo[TB];
    __shared__ int lcur[TB];
    for (int i = threadIdx.x; i < TB; i += P1T) hist[i] = 0;
    __syncthreads();
    const int* src; const int* dst; int E, l, g;
    decode_chunk(blockIdx.x, nc1, nc2, s1, d1, E1, s2, d2, E2, s3, d3, E3,
                 &src, &dst, &E, &l, &g);
    const int e0 = g * CH;
    const int lbase = l * NB;
    unsigned pv[EPT];
    int bn[EPT];
    if (E - e0 >= CH) {
        const int4* s4 = (const int4*)(src + e0);
        const int4* d4 = (const int4*)(dst + e0);
#pragma unroll
        for (int w = 0; w < EPT / 4; ++w) {
            int4 sv = s4[threadIdx.x + w * P1T];
            int4 dv = d4[threadIdx.x + w * P1T];
            int q, i = w * 4;
            q = dv.x / W; bn[i+0] = lbase + q; pv[i+0] = ((unsigned)sv.x << 9) | (unsigned)(dv.x - q * W);
            q = dv.y / W; bn[i+1] = lbase + q; pv[i+1] = ((unsigned)sv.y << 9) | (unsigned)(dv.y - q * W);
            q = dv.z / W; bn[i+2] = lbase + q; pv[i+2] = ((unsigned)sv.z << 9) | (unsigned)(dv.z - q * W);
            q = dv.w / W; bn[i+3] = lbase + q; pv[i+3] = ((unsigned)sv.w << 9) | (unsigned)(dv.w - q * W);
        }
    } else {
#pragma unroll
        for (int i = 0; i < EPT; ++i) {
            int e = e0 + threadIdx.x + i * P1T;
            if (e < E) {
                int s = src[e], d = dst[e];
                int q = d / W;
                bn[i] = lbase + q;
                pv[i] = ((unsigned)s << 9) | (unsigned)(d - q * W);
            } else bn[i] = -1;
        }
    }
#pragma unroll
    for (int i = 0; i < EPT; ++i)
        if (bn[i] >= 0) atomicAdd(&hist[bn[i]], 1);
    __syncthreads();
    for (int i = threadIdx.x; i < TB; i += P1T) {
        int c = hist[i];
        bo[i] = i * CAPE + (c ? atomicAdd(&gcur[i], c) : 0);
        lcur[i] = 0;
    }
    __syncthreads();
#pragma unroll
    for (int i = 0; i < EPT; ++i) {
        if (bn[i] >= 0) {
            int r = atomicAdd(&lcur[bn[i]], 1);
            int pos = bo[bn[i]] + r;
            if (pos < (bn[i] + 1) * CAPE) pairBuf[pos] = pv[i];
        }
    }
}

// K2: blocks [0,TB) = phase2 (u16 eidx); blocks [TB,...) = raw gemm1 -> fp16 h1.
__global__ void __launch_bounds__(P2T) k2_phase2_gemm1(
        const unsigned int* __restrict__ pairBuf, const int* __restrict__ gcur,
        int n, int W,
        int* __restrict__ row_ptr, int* __restrict__ cnt_g,
        float* __restrict__ dinv, unsigned short* __restrict__ eidx,
        const float* __restrict__ x0, const float* __restrict__ W1g,
        __half* __restrict__ h1) {
    __shared__ __align__(16) char smem[17408];
    if (blockIdx.x < (unsigned)TB) {
        int* lcnt  = (int*)smem;
        int* lscan = lcnt + P2T;
        unsigned short* stage = (unsigned short*)(lscan + P2T);
        const int bid = blockIdx.x;
        const int l = bid / NB, k = bid % NB;
        const int lo = k * W;
        const int hi = min(n, lo + W);
        const int Wn = hi - lo;
        const int segE = min(gcur[bid], CAPE);
        const size_t base  = (size_t)bid * CAPE;
        const int    baseE = bid * CAPE_E;
        const int t = threadIdx.x;
        lcnt[t] = 0;
        __syncthreads();
        for (int i = t; i < segE; i += P2T)
            atomicAdd(&lcnt[pairBuf[base + i] & 511u], 1);
        __syncthreads();
        const int v = lcnt[t];
        const int vp = (v + 3) & ~3;
        lscan[t] = vp;
        __syncthreads();
        for (int off = 1; off < P2T; off <<= 1) {
            int add = (t >= off) ? lscan[t - off] : 0;
            __syncthreads();
            lscan[t] += add;
            __syncthreads();
        }
        const int pexcl = lscan[t] - vp;
        const int segEp = lscan[P2T - 1];
        if (t < Wn) {
            int node = l * n + lo + t;
            row_ptr[node] = baseE + pexcl;
            cnt_g[node] = v;
            dinv[node] = rsqrtf((float)v + 1.0f);   // +1 self-loop
        }
        __syncthreads();
        lcnt[t] = pexcl;
        __syncthreads();
        const bool lds_ok = (segEp <= CAPE);
        for (int i = t; i < segE; i += P2T) {
            unsigned p = pairBuf[base + i];
            int pos = atomicAdd(&lcnt[p & 511u], 1);
            unsigned short s = (unsigned short)(p >> 9);
            if (lds_ok) stage[pos] = s;
            else if (pos < CAPE_E) eidx[baseE + pos] = s;
        }
        __syncthreads();
        if (lds_ok) {
            const int4* st4 = (const int4*)stage;
            int4* e4 = (int4*)(eidx + baseE);
            int m16 = (segEp + 7) >> 3;
            for (int i = t; i < m16; i += P2T) e4[i] = st4[i];
        }
    } else {
        float* Ws = (float*)smem;               // 16 KB
        const int bid = blockIdx.x - TB;
        for (int i = threadIdx.x; i < 1024; i += P2T)
            ((float4*)Ws)[i] = ((const float4*)W1g)[i];
        __syncthreads();
        const int tc = threadIdx.x % 16;
        const int tr = threadIdx.x / 16;
        const int row0 = bid * 128 + tr * 4;
        const float4* x4 = (const float4*)x0;
        const float4* Ws4 = (const float4*)Ws;
        float4 acc[4];
#pragma unroll
        for (int r = 0; r < 4; ++r) acc[r] = make_float4(0.f, 0.f, 0.f, 0.f);
        int rowc[4];
#pragma unroll
        for (int r = 0; r < 4; ++r) rowc[r] = min(row0 + r, n - 1);
        for (int k0 = 0; k0 < 64; k0 += 4) {
            float4 wv0 = Ws4[(k0 + 0) * 16 + tc];
            float4 wv1 = Ws4[(k0 + 1) * 16 + tc];
            float4 wv2 = Ws4[(k0 + 2) * 16 + tc];
            float4 wv3 = Ws4[(k0 + 3) * 16 + tc];
#pragma unroll
            for (int r = 0; r < 4; ++r) {
                float4 xv = x4[(size_t)rowc[r] * 16 + (k0 / 4)];
                fma4(acc[r], xv.x, wv0);
                fma4(acc[r], xv.y, wv1);
                fma4(acc[r], xv.z, wv2);
                fma4(acc[r], xv.w, wv3);
            }
        }
#pragma unroll
        for (int r = 0; r < 4; ++r) {
            int row = row0 + r;
            if (row < n) sth4(h1, (size_t)row * 16 + tc, acc[r]);
        }
    }
}

// K3: gather1 (fp16 h1, fp32 accumulate) + fused gemm2 -> fp16 h2.
// 256 thr = 16 nodes x 16 lanes.
__global__ void __launch_bounds__(256) k3_gather1_gemm2(
        const int* __restrict__ row_ptr, const int* __restrict__ cnt,
        const unsigned short* __restrict__ eidx, const float* __restrict__ dinv1,
        const __half* __restrict__ h1, const float* __restrict__ b1,
        const float* __restrict__ W2g, __half* __restrict__ h2, int n) {
    __shared__ float xs[16 * 68];
    __shared__ float W2s[64 * 32];
    for (int i = threadIdx.x; i < 512; i += 256)
        ((float4*)W2s)[i] = ((const float4*)W2g)[i];
    const int ln = threadIdx.x >> 4;
    const int f4 = threadIdx.x & 15;
    const int node = blockIdx.x * 16 + ln;
    if (node < n) {
        const int beg = row_ptr[node];
        const int m = cnt[node];
        float4 a0 = make_float4(0.f, 0.f, 0.f, 0.f), a1 = a0, a2 = a0, a3 = a0;
        int j = 0;
        for (; j + 8 <= m; j += 8) {
            ushort4 e0 = *(const ushort4*)(eidx + beg + j);
            ushort4 e1 = *(const ushort4*)(eidx + beg + j + 4);
            float w0 = dinv1[e0.x], w1 = dinv1[e0.y], w2 = dinv1[e0.z], w3 = dinv1[e0.w];
            float w4 = dinv1[e1.x], w5 = dinv1[e1.y], w6 = dinv1[e1.z], w7 = dinv1[e1.w];
            float4 v0 = ldh4(h1, (size_t)e0.x * 16 + f4);
            float4 v1 = ldh4(h1, (size_t)e0.y * 16 + f4);
            float4 v2 = ldh4(h1, (size_t)e0.z * 16 + f4);
            float4 v3 = ldh4(h1, (size_t)e0.w * 16 + f4);
            float4 v4 = ldh4(h1, (size_t)e1.x * 16 + f4);
            float4 v5 = ldh4(h1, (size_t)e1.y * 16 + f4);
            float4 v6 = ldh4(h1, (size_t)e1.z * 16 + f4);
            float4 v7 = ldh4(h1, (size_t)e1.w * 16 + f4);
            fma4(a0, w0, v0); fma4(a1, w1, v1); fma4(a2, w2, v2); fma4(a3, w3, v3);
            fma4(a0, w4, v4); fma4(a1, w5, v5); fma4(a2, w6, v6); fma4(a3, w7, v7);
        }
        if (j + 4 <= m) {
            ushort4 e0 = *(const ushort4*)(eidx + beg + j);
            fma4(a0, dinv1[e0.x], ldh4(h1, (size_t)e0.x * 16 + f4));
            fma4(a1, dinv1[e0.y], ldh4(h1, (size_t)e0.y * 16 + f4));
            fma4(a2, dinv1[e0.z], ldh4(h1, (size_t)e0.z * 16 + f4));
            fma4(a3, dinv1[e0.w], ldh4(h1, (size_t)e0.w * 16 + f4));
            j += 4;
        }
        for (; j < m; ++j) {
            int s = eidx[beg + j];
            fma4(a0, dinv1[s], ldh4(h1, (size_t)s * 16 + f4));
        }
        add4(a0, a1); add4(a2, a3); add4(a0, a2);
        float di = dinv1[node];
        float4 self = ldh4(h1, (size_t)node * 16 + f4);
        float4 bv = ((const float4*)b1)[f4];
        float4 o;
        o.x = di * (a0.x + di * self.x) + bv.x;
        o.y = di * (a0.y + di * self.y) + bv.y;
        o.z = di * (a0.z + di * self.z) + bv.z;
        o.w = di * (a0.w + di * self.w) + bv.w;
        o.x = o.x > 0.f ? o.x : 0.f;
        o.y = o.y > 0.f ? o.y : 0.f;
        o.z = o.z > 0.f ? o.z : 0.f;
        o.w = o.w > 0.f ? o.w : 0.f;
        *(float4*)&xs[ln * 68 + f4 * 4] = o;   // x1 row, LDS only (fp32)
    }
    __syncthreads();
    if (node < n) {
        const int c0 = f4 * 2;
        float s0 = 0.f, s1 = 0.f;
#pragma unroll
        for (int k = 0; k < 64; ++k) {
            float xv = xs[ln * 68 + k];
            s0 += xv * W2s[k * 32 + c0];
            s1 += xv * W2s[k * 32 + c0 + 1];
        }
        ((__half2*)h2)[(size_t)node * 16 + f4] = __floats2half2_rn(s0, s1);
    }
}

// K4: gather2 (fp16 h2) + fused gemm3 -> fp16 h3. 256 thr = 32 nodes x 8 lanes.
__global__ void __launch_bounds__(256) k4_gather2_gemm3(
        const int* __restrict__ row_ptr2, const int* __restrict__ cnt2,
        const unsigned short* __restrict__ eidx, const float* __restrict__ dinv2,
        const __half* __restrict__ h2, const float* __restrict__ b2,
        const float* __restrict__ W3g, __half* __restrict__ h3, int n) {
    __shared__ float xs[32 * 36];
    __shared__ float W3s[32 * 16];
    for (int i = threadIdx.x; i < 128; i += 256)
        ((float4*)W3s)[i] = ((const float4*)W3g)[i];
    const int ln = threadIdx.x >> 3;
    const int f4 = threadIdx.x & 7;
    const int node = blockIdx.x * 32 + ln;
    if (node < n) {
        const int beg = row_ptr2[node];
        const int m = cnt2[node];
        float4 a0 = make_float4(0.f, 0.f, 0.f, 0.f), a1 = a0, a2 = a0, a3 = a0;
        int j = 0;
        for (; j + 8 <= m; j += 8) {
            ushort4 e0 = *(const ushort4*)(eidx + beg + j);
            ushort4 e1 = *(const ushort4*)(eidx + beg + j + 4);
            float w0 = dinv2[e0.x], w1 = dinv2[e0.y], w2 = dinv2[e0.z], w3 = dinv2[e0.w];
            float w4 = dinv2[e1.x], w5 = dinv2[e1.y], w6 = dinv2[e1.z], w7 = dinv2[e1.w];
            fma4(a0, w0, ldh4(h2, (size_t)e0.x * 8 + f4));
            fma4(a1, w1, ldh4(h2, (size_t)e0.y * 8 + f4));
            fma4(a2, w2, ldh4(h2, (size_t)e0.z * 8 + f4));
            fma4(a3, w3, ldh4(h2, (size_t)e0.w * 8 + f4));
            fma4(a0, w4, ldh4(h2, (size_t)e1.x * 8 + f4));
            fma4(a1, w5, ldh4(h2, (size_t)e1.y * 8 + f4));
            fma4(a2, w6, ldh4(h2, (size_t)e1.z * 8 + f4));
            fma4(a3, w7, ldh4(h2, (size_t)e1.w * 8 + f4));
        }
        if (j + 4 <= m) {
            ushort4 e0 = *(const ushort4*)(eidx + beg + j);
            fma4(a0, dinv2[e0.x], ldh4(h2, (size_t)e0.x * 8 + f4));
            fma4(a1, dinv2[e0.y], ldh4(h2, (size_t)e0.y * 8 + f4));
            fma4(a2, dinv2[e0.z], ldh4(h2, (size_t)e0.z * 8 + f4));
            fma4(a3, dinv2[e0.w], ldh4(h2, (size_t)e0.w * 8 + f4));
            j += 4;
        }
        for (; j < m; ++j) {
            int s = eidx[beg + j];
            fma4(a0, dinv2[s], ldh4(h2, (size_t)s * 8 + f4));
        }
        add4(a0, a1); add4(a2, a3); add4(a0, a2);
        float di = dinv2[node];
        float4 self = ldh4(h2, (size_t)node * 8 + f4);
        float4 bv = ((const float4*)b2)[f4];
        float4 o;
        o.x = di * (a0.x + di * self.x) + bv.x;
        o.y = di * (a0.y + di * self.y) + bv.y;
        o.z = di * (a0.z + di * self.z) + bv.z;
        o.w = di * (a0.w + di * self.w) + bv.w;
        o.x = o.x > 0.f ? o.x : 0.f;
        o.y = o.y > 0.f ? o.y : 0.f;
        o.z = o.z > 0.f ? o.z : 0.f;
        o.w = o.w > 0.f ? o.w : 0.f;
        *(float4*)&xs[ln * 36 + f4 * 4] = o;   // x2 row, LDS only (fp32)
    }
    __syncthreads();
    if (node < n) {
        const int c0 = f4 * 2;
        float s0 = 0.f, s1 = 0.f;
#pragma unroll
        for (int k = 0; k < 32; ++k) {
            float xv = xs[ln * 36 + k];
            s0 += xv * W3s[k * 16 + c0];
            s1 += xv * W3s[k * 16 + c0 + 1];
        }
        ((__half2*)h3)[(size_t)node * 8 + f4] = __floats2half2_rn(s0, s1);
    }
}

// K5: gather3 (fp16 h3) -> fp32 out. 256 thr = 64 nodes x 4 lanes.
__global__ void __launch_bounds__(256) k5_gather3(
        const int* __restrict__ row_ptr3, const int* __restrict__ cnt3,
        const unsigned short* __restrict__ eidx, const float* __restrict__ dinv3,
        const __half* __restrict__ h3, const float* __restrict__ b3,
        float* __restrict__ out, int n) {
    const int ln = threadIdx.x >> 2;
    const int f4 = threadIdx.x & 3;
    const int node = blockIdx.x * 64 + ln;
    if (node >= n) return;
    const int beg = row_ptr3[node];
    const int m = cnt3[node];
    float4 a0 = make_float4(0.f, 0.f, 0.f, 0.f), a1 = a0, a2 = a0, a3 = a0;
    int j = 0;
    for (; j + 8 <= m; j += 8) {
        ushort4 e0 = *(const ushort4*)(eidx + beg + j);
        ushort4 e1 = *(const ushort4*)(eidx + beg + j + 4);
        float w0 = dinv3[e0.x], w1 = dinv3[e0.y], w2 = dinv3[e0.z], w3 = dinv3[e0.w];
        float w4 = dinv3[e1.x], w5 = dinv3[e1.y], w6 = dinv3[e1.z], w7 = dinv3[e1.w];
        fma4(a0, w0, ldh4(h3, (size_t)e0.x * 4 + f4));
        fma4(a1, w1, ldh4(h3, (size_t)e0.y * 4 + f4));
        fma4(a2, w2, ldh4(h3, (size_t)e0.z * 4 + f4));
        fma4(a3, w3, ldh4(h3, (size_t)e0.w * 4 + f4));
        fma4(a0, w4, ldh4(h3, (size_t)e1.x * 4 + f4));
        fma4(a1, w5, ldh4(h3, (size_t)e1.y * 4 + f4));
        fma4(a2, w6, ldh4(h3, (size_t)e1.z * 4 + f4));
        fma4(a3, w7, ldh4(h3, (size_t)e1.w * 4 + f4));
    }
    if (j + 4 <= m) {
        ushort4 e0 = *(const ushort4*)(eidx + beg + j);
        fma4(a0, dinv3[e0.x], ldh4(h3, (size_t)e0.x * 4 + f4));
        fma4(a1, dinv3[e0.y], ldh4(h3, (size_t)e0.y * 4 + f4));
        fma4(a2, dinv3[e0.z], ldh4(h3, (size_t)e0.z * 4 + f4));
        fma4(a3, dinv3[e0.w], ldh4(h3, (size_t)e0.w * 4 + f4));
        j += 4;
    }
    for (; j < m; ++j) {
        int s = eidx[beg + j];
        fma4(a0, dinv3[s], ldh4(h3, (size_t)s * 4 + f4));
    }
    add4(a0, a1); add4(a2, a3); add4(a0, a2);
    float di = dinv3[node];
    float4 self = ldh4(h3, (size_t)node * 4 + f4);
    float4 bv = ((const float4*)b3)[f4];
    float4 o;
    o.x = di * (a0.x + di * self.x) + bv.x;
    o.y = di * (a0.y + di * self.y) + bv.y;
    o.z = di * (a0.z + di * self.z) + bv.z;
    o.w = di * (a0.w + di * self.w) + bv.w;
    o.x = o.x > 0.f ? o.x : 0.f;
    o.y = o.y > 0.f ? o.y : 0.f;
    o.z = o.z > 0.f ? o.z : 0.f;
    o.w = o.w > 0.f ? o.w : 0.f;
    ((float4*)out)[(size_t)node * 4 + f4] = o;
}

extern "C" void kernel_launch(void* const* d_in, const int* in_sizes, int n_in,
                              void* d_out, int out_size, void* d_ws, size_t ws_size,
                              hipStream_t stream) {
    const float* x0  = (const float*)d_in[0];
    const int*   ei1 = (const int*)d_in[1];
    const int*   ei3 = (const int*)d_in[2];
    const int*   ei9 = (const int*)d_in[3];
    const float* W1  = (const float*)d_in[4];
    const float* b1  = (const float*)d_in[5];
    const float* W2  = (const float*)d_in[6];
    const float* b2  = (const float*)d_in[7];
    const float* W3  = (const float*)d_in[8];
    const float* b3  = (const float*)d_in[9];

    const int n  = in_sizes[0] / 64;  // 50000
    const int E1 = in_sizes[1] / 2;   // 800000
    const int E3 = in_sizes[2] / 2;
    const int E9 = in_sizes[3] / 2;
    const int n3 = 3 * n;
    const int W  = (n + NB - 1) / NB; // 196

    const int nc1 = (E1 + CH - 1) / CH;
    const int nc2 = (E3 + CH - 1) / CH;
    const int nc3 = (E9 + CH - 1) / CH;
    const int nchunks = nc1 + nc2 + nc3;
    const int gemmBlks = (n + 127) / 128;

    int* gcur    = (int*)d_ws;                           // TB
    unsigned int* pairBuf = (unsigned int*)(gcur + TB);  // TB*CAPE u32
    unsigned short* eidx = (unsigned short*)(pairBuf + (size_t)TB * CAPE); // TB*CAPE_E u16
    int* row_ptr = (int*)(eidx + (size_t)TB * CAPE_E);   // 3n
    int* cnt     = row_ptr + n3;                         // 3n
    float* dinv  = (float*)(cnt + n3);                   // 3n
    __half* h1   = (__half*)(dinv + n3);                 // n*64 fp16
    __half* h2   = h1 + (size_t)n * 64;                  // n*32 fp16
    __half* h3   = h2 + (size_t)n * 32;                  // n*16 fp16

    hipMemsetAsync(gcur, 0, TB * sizeof(int), stream);
    phase1<<<nchunks, P1T, 0, stream>>>(ei1, ei1 + E1, E1, ei3, ei3 + E3, E3,
                                        ei9, ei9 + E9, E9, nc1, nc2, W, gcur, pairBuf);
    k2_phase2_gemm1<<<TB + gemmBlks, P2T, 0, stream>>>(
        pairBuf, gcur, n, W, row_ptr, cnt, dinv, eidx, x0, W1, h1);
    k3_gather1_gemm2<<<(n + 15) / 16, 256, 0, stream>>>(
        row_ptr, cnt, eidx, dinv, h1, b1, W2, h2, n);
    k4_gather2_gemm3<<<(n + 31) / 32, 256, 0, stream>>>(
        row_ptr + n, cnt + n, eidx, dinv + n, h2, b2, W3, h3, n);
    k5_gather3<<<(n + 63) / 64, 256, 0, stream>>>(
        row_ptr + 2 * n, cnt + 2 * n, eidx, dinv + 2 * n, h3, b3, (float*)d_out, n);
}

// Round 14
// 176.327 us; speedup vs baseline: 1.5876x; 1.0299x over previous
//
#include <hip/hip_runtime.h>
#include <hip/hip_fp16.h>

// ---------------------------------------------------------------------------
// 3-layer GCN, 5 dispatches:
//  K1: phase1 bucket-sort (counting sort into per-bucket arena, dense writes)
//  K2: [phase2 per-bucket node sort -> row_ptr/cnt/dinv + u16 eidx (768 wgs)]
//      ∥ [raw gemm1 h1 = x0 @ W1 (rest)]
//  K3: gather1 (per-edge dinv1[s] FMA over fp16 h1) + gemm2 -> h2' = dinv2*(x1@W2)
//  K4: gather2 (plain adds over prescaled h2') + gemm3 -> h3' = dinv3*(x2@W3)
//  K5: gather3 (plain adds over prescaled h3') -> out
// h* fp16 (fp32 accumulate): gathers are LLC-BW-bound at ~8 XCDs x |h|
// (R7/R10); fp16 halved that (R11: -19us). Prescaled h2'/h3' remove the
// per-edge dinv broadcast loads in K4/K5.
// NOTE (R6): f32 LDS atomicAdd is a serializing slow path on gfx950.
// NOTE (R8): never co-schedule streaming traffic with phase1's 4B scatter.
// NOTE (R12): hipLaunchCooperativeKernel fails silently under this harness's
// graph capture (output stays zero) — regular launches only.
// ---------------------------------------------------------------------------

#define NB   256            // buckets per layer (W = ceil(n/NB) = 196 < 512)
#define NL   3
#define TB   (NB * NL)      // 768 buckets
#define CAPE 6400           // arena capacity per bucket (mean fill ~3125)
#define CAPE_E (CAPE + 8)   // u16 eidx arena stride (+8 spill room)
#define CH   8192           // edges per phase-1 chunk
#define P1T  512
#define EPT  (CH / P1T)
#define P2T  512

__device__ __forceinline__ void decode_chunk(int g, int nc1, int nc2,
                                             const int* s1, const int* d1, int E1,
                                             const int* s2, const int* d2, int E2,
                                             const int* s3, const int* d3, int E3,
                                             const int** src, const int** dst, int* E, int* l,
                                             int* gout) {
    if (g < nc1)            { *src = s1; *dst = d1; *E = E1; *l = 0; }
    else if (g < nc1 + nc2) { *src = s2; *dst = d2; *E = E2; *l = 1; g -= nc1; }
    else                    { *src = s3; *dst = d3; *E = E3; *l = 2; g -= nc1 + nc2; }
    *gout = g;
}

__device__ __forceinline__ void fma4(float4& a, float s, const float4& w) {
    a.x += s * w.x; a.y += s * w.y; a.z += s * w.z; a.w += s * w.w;
}
__device__ __forceinline__ void add4(float4& a, const float4& v) {
    a.x += v.x; a.y += v.y; a.z += v.z; a.w += v.w;
}
__device__ __forceinline__ float4 ldh4(const __half* h, size_t idx4) {
    uint2 r = ((const uint2*)h)[idx4];
    __half2 a = *reinterpret_cast<__half2*>(&r.x);
    __half2 b = *reinterpret_cast<__half2*>(&r.y);
    float2 fa = __half22float2(a), fb = __half22float2(b);
    return make_float4(fa.x, fa.y, fb.x, fb.y);
}
__device__ __forceinline__ void sth4(__half* h, size_t idx4, float4 v) {
    __half2 a = __floats2half2_rn(v.x, v.y);
    __half2 b = __floats2half2_rn(v.z, v.w);
    uint2 r;
    r.x = *reinterpret_cast<unsigned*>(&a);
    r.y = *reinterpret_cast<unsigned*>(&b);
    ((uint2*)h)[idx4] = r;
}

__global__ void __launch_bounds__(P1T) phase1(
        const int* __restrict__ s1, const int* __restrict__ d1, int E1,
        const int* __restrict__ s2, const int* __restrict__ d2, int E2,
        const int* __restrict__ s3, const int* __restrict__ d3, int E3,
        int nc1, int nc2, int W,
        int* __restrict__ gcur, unsigned int* __restrict__ pairBuf) {
    __shared__ int hist[TB];
    __shared__ int bo[TB];
    __shared__ int lcur[TB];
    for (int i = threadIdx.x; i < TB; i += P1T) hist[i] = 0;
    __syncthreads();
    const int* src; const int* dst; int E, l, g;
    decode_chunk(blockIdx.x, nc1, nc2, s1, d1, E1, s2, d2, E2, s3, d3, E3,
                 &src, &dst, &E, &l, &g);
    const int e0 = g * CH;
    const int lbase = l * NB;
    unsigned pv[EPT];
    int bn[EPT];
    if (E - e0 >= CH) {
        const int4* s4 = (const int4*)(src + e0);
        const int4* d4 = (const int4*)(dst + e0);
#pragma unroll
        for (int w = 0; w < EPT / 4; ++w) {
            int4 sv = s4[threadIdx.x + w * P1T];
            int4 dv = d4[threadIdx.x + w * P1T];
            int q, i = w * 4;
            q = dv.x / W; bn[i+0] = lbase + q; pv[i+0] = ((unsigned)sv.x << 9) | (unsigned)(dv.x - q * W);
            q = dv.y / W; bn[i+1] = lbase + q; pv[i+1] = ((unsigned)sv.y << 9) | (unsigned)(dv.y - q * W);
            q = dv.z / W; bn[i+2] = lbase + q; pv[i+2] = ((unsigned)sv.z << 9) | (unsigned)(dv.z - q * W);
            q = dv.w / W; bn[i+3] = lbase + q; pv[i+3] = ((unsigned)sv.w << 9) | (unsigned)(dv.w - q * W);
        }
    } else {
#pragma unroll
        for (int i = 0; i < EPT; ++i) {
            int e = e0 + threadIdx.x + i * P1T;
            if (e < E) {
                int s = src[e], d = dst[e];
                int q = d / W;
                bn[i] = lbase + q;
                pv[i] = ((unsigned)s << 9) | (unsigned)(d - q * W);
            } else bn[i] = -1;
        }
    }
#pragma unroll
    for (int i = 0; i < EPT; ++i)
        if (bn[i] >= 0) atomicAdd(&hist[bn[i]], 1);
    __syncthreads();
    for (int i = threadIdx.x; i < TB; i += P1T) {
        int c = hist[i];
        bo[i] = i * CAPE + (c ? atomicAdd(&gcur[i], c) : 0);
        lcur[i] = 0;
    }
    __syncthreads();
#pragma unroll
    for (int i = 0; i < EPT; ++i) {
        if (bn[i] >= 0) {
            int r = atomicAdd(&lcur[bn[i]], 1);
            int pos = bo[bn[i]] + r;
            if (pos < (bn[i] + 1) * CAPE) pairBuf[pos] = pv[i];
        }
    }
}

// K2: blocks [0,TB) = phase2 (u16 eidx); blocks [TB,...) = raw gemm1 -> fp16 h1.
__global__ void __launch_bounds__(P2T) k2_phase2_gemm1(
        const unsigned int* __restrict__ pairBuf, const int* __restrict__ gcur,
        int n, int W,
        int* __restrict__ row_ptr, int* __restrict__ cnt_g,
        float* __restrict__ dinv, unsigned short* __restrict__ eidx,
        const float* __restrict__ x0, const float* __restrict__ W1g,
        __half* __restrict__ h1) {
    __shared__ __align__(16) char smem[17408];
    if (blockIdx.x < (unsigned)TB) {
        int* lcnt  = (int*)smem;
        int* lscan = lcnt + P2T;
        unsigned short* stage = (unsigned short*)(lscan + P2T);
        const int bid = blockIdx.x;
        const int l = bid / NB, k = bid % NB;
        const int lo = k * W;
        const int hi = min(n, lo + W);
        const int Wn = hi - lo;
        const int segE = min(gcur[bid], CAPE);
        const size_t base  = (size_t)bid * CAPE;
        const int    baseE = bid * CAPE_E;
        const int t = threadIdx.x;
        lcnt[t] = 0;
        __syncthreads();
        for (int i = t; i < segE; i += P2T)
            atomicAdd(&lcnt[pairBuf[base + i] & 511u], 1);
        __syncthreads();
        const int v = lcnt[t];
        const int vp = (v + 3) & ~3;
        lscan[t] = vp;
        __syncthreads();
        for (int off = 1; off < P2T; off <<= 1) {
            int add = (t >= off) ? lscan[t - off] : 0;
            __syncthreads();
            lscan[t] += add;
            __syncthreads();
        }
        const int pexcl = lscan[t] - vp;
        const int segEp = lscan[P2T - 1];
        if (t < Wn) {
            int node = l * n + lo + t;
            row_ptr[node] = baseE + pexcl;
            cnt_g[node] = v;
            dinv[node] = rsqrtf((float)v + 1.0f);   // +1 self-loop
        }
        __syncthreads();
        lcnt[t] = pexcl;
        __syncthreads();
        const bool lds_ok = (segEp <= CAPE);
        for (int i = t; i < segE; i += P2T) {
            unsigned p = pairBuf[base + i];
            int pos = atomicAdd(&lcnt[p & 511u], 1);
            unsigned short s = (unsigned short)(p >> 9);
            if (lds_ok) stage[pos] = s;
            else if (pos < CAPE_E) eidx[baseE + pos] = s;
        }
        __syncthreads();
        if (lds_ok) {
            const int4* st4 = (const int4*)stage;
            int4* e4 = (int4*)(eidx + baseE);
            int m16 = (segEp + 7) >> 3;
            for (int i = t; i < m16; i += P2T) e4[i] = st4[i];
        }
    } else {
        float* Ws = (float*)smem;               // 16 KB
        const int bid = blockIdx.x - TB;
        for (int i = threadIdx.x; i < 1024; i += P2T)
            ((float4*)Ws)[i] = ((const float4*)W1g)[i];
        __syncthreads();
        const int tc = threadIdx.x % 16;
        const int tr = threadIdx.x / 16;
        const int row0 = bid * 128 + tr * 4;
        const float4* x4 = (const float4*)x0;
        const float4* Ws4 = (const float4*)Ws;
        float4 acc[4];
#pragma unroll
        for (int r = 0; r < 4; ++r) acc[r] = make_float4(0.f, 0.f, 0.f, 0.f);
        int rowc[4];
#pragma unroll
        for (int r = 0; r < 4; ++r) rowc[r] = min(row0 + r, n - 1);
        for (int k0 = 0; k0 < 64; k0 += 4) {
            float4 wv0 = Ws4[(k0 + 0) * 16 + tc];
            float4 wv1 = Ws4[(k0 + 1) * 16 + tc];
            float4 wv2 = Ws4[(k0 + 2) * 16 + tc];
            float4 wv3 = Ws4[(k0 + 3) * 16 + tc];
#pragma unroll
            for (int r = 0; r < 4; ++r) {
                float4 xv = x4[(size_t)rowc[r] * 16 + (k0 / 4)];
                fma4(acc[r], xv.x, wv0);
                fma4(acc[r], xv.y, wv1);
                fma4(acc[r], xv.z, wv2);
                fma4(acc[r], xv.w, wv3);
            }
        }
#pragma unroll
        for (int r = 0; r < 4; ++r) {
            int row = row0 + r;
            if (row < n) sth4(h1, (size_t)row * 16 + tc, acc[r]);
        }
    }
}

// K3: gather1 (fp16 h1, per-edge dinv1 FMA) + fused gemm2 -> h2' = dinv2*(x1@W2).
// 256 thr = 16 nodes x 16 lanes.
__global__ void __launch_bounds__(256) k3_gather1_gemm2(
        const int* __restrict__ row_ptr, const int* __restrict__ cnt,
        const unsigned short* __restrict__ eidx, const float* __restrict__ dinv1,
        const float* __restrict__ dinv2,
        const __half* __restrict__ h1, const float* __restrict__ b1,
        const float* __restrict__ W2g, __half* __restrict__ h2, int n) {
    __shared__ float xs[16 * 68];
    __shared__ float W2s[64 * 32];
    for (int i = threadIdx.x; i < 512; i += 256)
        ((float4*)W2s)[i] = ((const float4*)W2g)[i];
    const int ln = threadIdx.x >> 4;
    const int f4 = threadIdx.x & 15;
    const int node = blockIdx.x * 16 + ln;
    if (node < n) {
        const int beg = row_ptr[node];
        const int m = cnt[node];
        float4 a0 = make_float4(0.f, 0.f, 0.f, 0.f), a1 = a0, a2 = a0, a3 = a0;
        int j = 0;
        for (; j + 8 <= m; j += 8) {
            ushort4 e0 = *(const ushort4*)(eidx + beg + j);
            ushort4 e1 = *(const ushort4*)(eidx + beg + j + 4);
            float w0 = dinv1[e0.x], w1 = dinv1[e0.y], w2 = dinv1[e0.z], w3 = dinv1[e0.w];
            float w4 = dinv1[e1.x], w5 = dinv1[e1.y], w6 = dinv1[e1.z], w7 = dinv1[e1.w];
            float4 v0 = ldh4(h1, (size_t)e0.x * 16 + f4);
            float4 v1 = ldh4(h1, (size_t)e0.y * 16 + f4);
            float4 v2 = ldh4(h1, (size_t)e0.z * 16 + f4);
            float4 v3 = ldh4(h1, (size_t)e0.w * 16 + f4);
            float4 v4 = ldh4(h1, (size_t)e1.x * 16 + f4);
            float4 v5 = ldh4(h1, (size_t)e1.y * 16 + f4);
            float4 v6 = ldh4(h1, (size_t)e1.z * 16 + f4);
            float4 v7 = ldh4(h1, (size_t)e1.w * 16 + f4);
            fma4(a0, w0, v0); fma4(a1, w1, v1); fma4(a2, w2, v2); fma4(a3, w3, v3);
            fma4(a0, w4, v4); fma4(a1, w5, v5); fma4(a2, w6, v6); fma4(a3, w7, v7);
        }
        if (j + 4 <= m) {
            ushort4 e0 = *(const ushort4*)(eidx + beg + j);
            fma4(a0, dinv1[e0.x], ldh4(h1, (size_t)e0.x * 16 + f4));
            fma4(a1, dinv1[e0.y], ldh4(h1, (size_t)e0.y * 16 + f4));
            fma4(a2, dinv1[e0.z], ldh4(h1, (size_t)e0.z * 16 + f4));
            fma4(a3, dinv1[e0.w], ldh4(h1, (size_t)e0.w * 16 + f4));
            j += 4;
        }
        for (; j < m; ++j) {
            int s = eidx[beg + j];
            fma4(a0, dinv1[s], ldh4(h1, (size_t)s * 16 + f4));
        }
        add4(a0, a1); add4(a2, a3); add4(a0, a2);
        float di = dinv1[node];
        float4 self = ldh4(h1, (size_t)node * 16 + f4);
        float4 bv = ((const float4*)b1)[f4];
        float4 o;
        o.x = di * (a0.x + di * self.x) + bv.x;
        o.y = di * (a0.y + di * self.y) + bv.y;
        o.z = di * (a0.z + di * self.z) + bv.z;
        o.w = di * (a0.w + di * self.w) + bv.w;
        o.x = o.x > 0.f ? o.x : 0.f;
        o.y = o.y > 0.f ? o.y : 0.f;
        o.z = o.z > 0.f ? o.z : 0.f;
        o.w = o.w > 0.f ? o.w : 0.f;
        *(float4*)&xs[ln * 68 + f4 * 4] = o;   // x1 row, LDS only (fp32)
    }
    __syncthreads();
    if (node < n) {
        const int c0 = f4 * 2;
        float s0 = 0.f, s1 = 0.f;
#pragma unroll
        for (int k = 0; k < 64; ++k) {
            float xv = xs[ln * 68 + k];
            s0 += xv * W2s[k * 32 + c0];
            s1 += xv * W2s[k * 32 + c0 + 1];
        }
        float d2 = dinv2[node];                 // prescale: h2' = dinv2 * h2raw
        ((__half2*)h2)[(size_t)node * 16 + f4] = __floats2half2_rn(s0 * d2, s1 * d2);
    }
}

// K4: gather2 (plain adds over prescaled h2') + fused gemm3 -> h3' = dinv3*(x2@W3).
// 256 thr = 32 nodes x 8 lanes.
__global__ void __launch_bounds__(256) k4_gather2_gemm3(
        const int* __restrict__ row_ptr2, const int* __restrict__ cnt2,
        const unsigned short* __restrict__ eidx, const float* __restrict__ dinv2,
        const float* __restrict__ dinv3,
        const __half* __restrict__ h2, const float* __restrict__ b2,
        const float* __restrict__ W3g, __half* __restrict__ h3, int n) {
    __shared__ float xs[32 * 36];
    __shared__ float W3s[32 * 16];
    for (int i = threadIdx.x; i < 128; i += 256)
        ((float4*)W3s)[i] = ((const float4*)W3g)[i];
    const int ln = threadIdx.x >> 3;
    const int f4 = threadIdx.x & 7;
    const int node = blockIdx.x * 32 + ln;
    if (node < n) {
        const int beg = row_ptr2[node];
        const int m = cnt2[node];
        float4 a0 = make_float4(0.f, 0.f, 0.f, 0.f), a1 = a0, a2 = a0, a3 = a0;
        int j = 0;
        for (; j + 8 <= m; j += 8) {
            ushort4 e0 = *(const ushort4*)(eidx + beg + j);
            ushort4 e1 = *(const ushort4*)(eidx + beg + j + 4);
            add4(a0, ldh4(h2, (size_t)e0.x * 8 + f4));
            add4(a1, ldh4(h2, (size_t)e0.y * 8 + f4));
            add4(a2, ldh4(h2, (size_t)e0.z * 8 + f4));
            add4(a3, ldh4(h2, (size_t)e0.w * 8 + f4));
            add4(a0, ldh4(h2, (size_t)e1.x * 8 + f4));
            add4(a1, ldh4(h2, (size_t)e1.y * 8 + f4));
            add4(a2, ldh4(h2, (size_t)e1.z * 8 + f4));
            add4(a3, ldh4(h2, (size_t)e1.w * 8 + f4));
        }
        if (j + 4 <= m) {
            ushort4 e0 = *(const ushort4*)(eidx + beg + j);
            add4(a0, ldh4(h2, (size_t)e0.x * 8 + f4));
            add4(a1, ldh4(h2, (size_t)e0.y * 8 + f4));
            add4(a2, ldh4(h2, (size_t)e0.z * 8 + f4));
            add4(a3, ldh4(h2, (size_t)e0.w * 8 + f4));
            j += 4;
        }
        for (; j < m; ++j)
            add4(a0, ldh4(h2, (size_t)eidx[beg + j] * 8 + f4));
        add4(a0, a1); add4(a2, a3); add4(a0, a2);
        float di = dinv2[node];
        float4 self = ldh4(h2, (size_t)node * 8 + f4);  // already dinv2*h2raw
        float4 bv = ((const float4*)b2)[f4];
        float4 o;
        o.x = di * (a0.x + self.x) + bv.x;
        o.y = di * (a0.y + self.y) + bv.y;
        o.z = di * (a0.z + self.z) + bv.z;
        o.w = di * (a0.w + self.w) + bv.w;
        o.x = o.x > 0.f ? o.x : 0.f;
        o.y = o.y > 0.f ? o.y : 0.f;
        o.z = o.z > 0.f ? o.z : 0.f;
        o.w = o.w > 0.f ? o.w : 0.f;
        *(float4*)&xs[ln * 36 + f4 * 4] = o;   // x2 row, LDS only (fp32)
    }
    __syncthreads();
    if (node < n) {
        const int c0 = f4 * 2;
        float s0 = 0.f, s1 = 0.f;
#pragma unroll
        for (int k = 0; k < 32; ++k) {
            float xv = xs[ln * 36 + k];
            s0 += xv * W3s[k * 16 + c0];
            s1 += xv * W3s[k * 16 + c0 + 1];
        }
        float d3 = dinv3[node];                 // prescale: h3' = dinv3 * h3raw
        ((__half2*)h3)[(size_t)node * 8 + f4] = __floats2half2_rn(s0 * d3, s1 * d3);
    }
}

// K5: gather3 (plain adds over prescaled h3') -> fp32 out. 64 nodes x 4 lanes.
__global__ void __launch_bounds__(256) k5_gather3(
        const int* __restrict__ row_ptr3, const int* __restrict__ cnt3,
        const unsigned short* __restrict__ eidx, const float* __restrict__ dinv3,
        const __half* __restrict__ h3, const float* __restrict__ b3,
        float* __restrict__ out, int n) {
    const int ln = threadIdx.x >> 2;
    const int f4 = threadIdx.x & 3;
    const int node = blockIdx.x * 64 + ln;
    if (node >= n) return;
    const int beg = row_ptr3[node];
    const int m = cnt3[node];
    float4 a0 = make_float4(0.f, 0.f, 0.f, 0.f), a1 = a0, a2 = a0, a3 = a0;
    int j = 0;
    for (; j + 8 <= m; j += 8) {
        ushort4 e0 = *(const ushort4*)(eidx + beg + j);
        ushort4 e1 = *(const ushort4*)(eidx + beg + j + 4);
        add4(a0, ldh4(h3, (size_t)e0.x * 4 + f4));
        add4(a1, ldh4(h3, (size_t)e0.y * 4 + f4));
        add4(a2, ldh4(h3, (size_t)e0.z * 4 + f4));
        add4(a3, ldh4(h3, (size_t)e0.w * 4 + f4));
        add4(a0, ldh4(h3, (size_t)e1.x * 4 + f4));
        add4(a1, ldh4(h3, (size_t)e1.y * 4 + f4));
        add4(a2, ldh4(h3, (size_t)e1.z * 4 + f4));
        add4(a3, ldh4(h3, (size_t)e1.w * 4 + f4));
    }
    if (j + 4 <= m) {
        ushort4 e0 = *(const ushort4*)(eidx + beg + j);
        add4(a0, ldh4(h3, (size_t)e0.x * 4 + f4));
        add4(a1, ldh4(h3, (size_t)e0.y * 4 + f4));
        add4(a2, ldh4(h3, (size_t)e0.z * 4 + f4));
        add4(a3, ldh4(h3, (size_t)e0.w * 4 + f4));
        j += 4;
    }
    for (; j < m; ++j)
        add4(a0, ldh4(h3, (size_t)eidx[beg + j] * 4 + f4));
    add4(a0, a1); add4(a2, a3); add4(a0, a2);
    float di = dinv3[node];
    float4 self = ldh4(h3, (size_t)node * 4 + f4);  // already dinv3*h3raw
    float4 bv = ((const float4*)b3)[f4];
    float4 o;
    o.x = di * (a0.x + self.x) + bv.x;
    o.y = di * (a0.y + self.y) + bv.y;
    o.z = di * (a0.z + self.z) + bv.z;
    o.w = di * (a0.w + self.w) + bv.w;
    o.x = o.x > 0.f ? o.x : 0.f;
    o.y = o.y > 0.f ? o.y : 0.f;
    o.z = o.z > 0.f ? o.z : 0.f;
    o.w = o.w > 0.f ? o.w : 0.f;
    ((float4*)out)[(size_t)node * 4 + f4] = o;
}

extern "C" void kernel_launch(void* const* d_in, const int* in_sizes, int n_in,
                              void* d_out, int out_size, void* d_ws, size_t ws_size,
                              hipStream_t stream) {
    const float* x0  = (const float*)d_in[0];
    const int*   ei1 = (const int*)d_in[1];
    const int*   ei3 = (const int*)d_in[2];
    const int*   ei9 = (const int*)d_in[3];
    const float* W1  = (const float*)d_in[4];
    const float* b1  = (const float*)d_in[5];
    const float* W2  = (const float*)d_in[6];
    const float* b2  = (const float*)d_in[7];
    const float* W3  = (const float*)d_in[8];
    const float* b3  = (const float*)d_in[9];

    const int n  = in_sizes[0] / 64;  // 50000
    const int E1 = in_sizes[1] / 2;   // 800000
    const int E3 = in_sizes[2] / 2;
    const int E9 = in_sizes[3] / 2;
    const int n3 = 3 * n;
    const int W  = (n + NB - 1) / NB; // 196

    const int nc1 = (E1 + CH - 1) / CH;
    const int nc2 = (E3 + CH - 1) / CH;
    const int nc3 = (E9 + CH - 1) / CH;
    const int nchunks = nc1 + nc2 + nc3;
    const int gemmBlks = (n + 127) / 128;

    int* gcur    = (int*)d_ws;                           // TB
    unsigned int* pairBuf = (unsigned int*)(gcur + TB);  // TB*CAPE u32
    unsigned short* eidx = (unsigned short*)(pairBuf + (size_t)TB * CAPE); // TB*CAPE_E u16
    int* row_ptr = (int*)(eidx + (size_t)TB * CAPE_E);   // 3n
    int* cnt     = row_ptr + n3;                         // 3n
    float* dinv  = (float*)(cnt + n3);                   // 3n
    __half* h1   = (__half*)(dinv + n3);                 // n*64 fp16
    __half* h2   = h1 + (size_t)n * 64;                  // n*32 fp16
    __half* h3   = h2 + (size_t)n * 32;                  // n*16 fp16

    hipMemsetAsync(gcur, 0, TB * sizeof(int), stream);
    phase1<<<nchunks, P1T, 0, stream>>>(ei1, ei1 + E1, E1, ei3, ei3 + E3, E3,
                                        ei9, ei9 + E9, E9, nc1, nc2, W, gcur, pairBuf);
    k2_phase2_gemm1<<<TB + gemmBlks, P2T, 0, stream>>>(
        pairBuf, gcur, n, W, row_ptr, cnt, dinv, eidx, x0, W1, h1);
    k3_gather1_gemm2<<<(n + 15) / 16, 256, 0, stream>>>(
        row_ptr, cnt, eidx, dinv, dinv + n, h1, b1, W2, h2, n);
    k4_gather2_gemm3<<<(n + 31) / 32, 256, 0, stream>>>(
        row_ptr + n, cnt + n, eidx, dinv + n, dinv + 2 * n, h2, b2, W3, h3, n);
    k5_gather3<<<(n + 63) / 64, 256, 0, stream>>>(
        row_ptr + 2 * n, cnt + 2 * n, eidx, dinv + 2 * n, h3, b3, (float*)d_out, n);
}